// Round 1
// baseline (503.313 us; speedup 1.0000x reference)
//
#include <hip/hip_runtime.h>

#define DEV __device__ __forceinline__

typedef __attribute__((ext_vector_type(8))) short s8v;
typedef __attribute__((ext_vector_type(4))) short s4v;
typedef __attribute__((ext_vector_type(4))) float f4v;

DEV unsigned short f2b(float f){
    unsigned u = __float_as_uint(f);
    u = (u + 0x7FFFu + ((u >> 16) & 1u)) >> 16;
    return (unsigned short)u;
}
DEV float b2f(short s){ return __uint_as_float(((unsigned)(unsigned short)s) << 16); }

// B=4, S=1024, D=1024, H=8, E=4, K=2, DH=128

// ---------------- transpose (fp32 in -> bf16 out), per-z slice [R][C] -> [C][R]
__global__ __launch_bounds__(256) void k_transpose(const float* in, short* out, int R, int C){
    in  += (size_t)blockIdx.z * R * C;
    out += (size_t)blockIdx.z * R * C;
    __shared__ float t[32][33];
    int c0 = blockIdx.x * 32, r0 = blockIdx.y * 32;
    int tx = threadIdx.x & 31, ty = threadIdx.x >> 5;
    #pragma unroll
    for(int p = 0; p < 4; p++){
        int r = p * 8 + ty;
        t[r][tx] = in[(size_t)(r0 + r) * C + c0 + tx];
    }
    __syncthreads();
    #pragma unroll
    for(int p = 0; p < 4; p++){
        int c = p * 8 + ty;
        out[(size_t)(c0 + c) * R + r0 + tx] = (short)f2b(t[tx][c]);
    }
}

// ---------------- routing: sigmoid gates + top-2 of E=4 per head, fp64 accumulation
__global__ __launch_bounds__(256) void k_route(const float* qsrc, const float* ksrc,
                                               const float* selv, const float* selo,
                                               float* wvp, float* wop){
    int which = blockIdx.y;
    const float* src = which ? qsrc : ksrc;
    const float* sel = which ? selo : selv;
    float* wout = which ? wop : wvp;
    int w = threadIdx.x >> 6, lane = threadIdx.x & 63;
    int token = blockIdx.x * 4 + w;
    const float4* srow = (const float4*)(src + (size_t)token * 1024 + lane * 16);
    float x[16];
    #pragma unroll
    for(int q = 0; q < 4; q++){
        float4 v = srow[q];
        x[q*4+0] = v.x; x[q*4+1] = v.y; x[q*4+2] = v.z; x[q*4+3] = v.w;
    }
    __shared__ float gs[4][32];
    for(int e = 0; e < 32; e++){
        const float4* sr = (const float4*)(sel + (size_t)e * 1024 + lane * 16);
        double acc = 0.0;
        #pragma unroll
        for(int q = 0; q < 4; q++){
            float4 v = sr[q];
            acc += (double)x[q*4+0] * (double)v.x;
            acc += (double)x[q*4+1] * (double)v.y;
            acc += (double)x[q*4+2] * (double)v.z;
            acc += (double)x[q*4+3] * (double)v.w;
        }
        #pragma unroll
        for(int off = 1; off < 64; off <<= 1) acc += __shfl_xor(acc, off);
        if(lane == 0) gs[w][e] = 1.0f / (1.0f + expf((float)(-acc)));
    }
    if(lane < 8){
        float g[4];
        #pragma unroll
        for(int e = 0; e < 4; e++) g[e] = gs[w][lane * 4 + e];
        // rank-based top-2, first-occurrence tie-break (matches lax.top_k)
        #pragma unroll
        for(int e = 0; e < 4; e++){
            int rank = 0;
            #pragma unroll
            for(int j = 0; j < 4; j++)
                rank += (g[j] > g[e]) || (g[j] == g[e] && j < e);
            wout[(size_t)token * 32 + lane * 4 + e] = (rank < 2) ? g[e] : 0.0f;
        }
    }
}

// ---------------- NT GEMM, 128x128 tile, BK=64, 4 waves (2x2 of 64x64)
// MODE 0: A fp32, B fp32, out = bf16 q/k scattered to [B,H,S,DH], *scale
// MODE 1: A fp32 (v_src), B bf16 (WvT), out = bf16 v_allw[token][he*128+c], * wv[token][he]
// MODE 2: A bf16 res (fused * wo[token][he] during staging, K=4096), B bf16 (WoT), out fp32 d_out
template<int MODE>
__global__ __launch_bounds__(256) void k_gemm(const void* Aptr, const void* Bptr, void* Cptr,
                                              int M, int N, int K, const float* gate, float scale){
    constexpr int LDT = 72;
    __shared__ __align__(16) short la[128 * LDT];
    __shared__ __align__(16) short lb[128 * LDT];
    int ntn = N >> 7;
    int mt = blockIdx.x / ntn, nt = blockIdx.x % ntn;
    int i0 = mt << 7, j0 = nt << 7;
    int tid = threadIdx.x, lane = tid & 63, w = tid >> 6;
    int wm = (w >> 1) << 6, wn = (w & 1) << 6;
    int qr = lane & 15, grp = lane >> 4;
    f4v acc[4][4];
    #pragma unroll
    for(int m = 0; m < 4; m++)
        #pragma unroll
        for(int n = 0; n < 4; n++) acc[m][n] = f4v{0.f, 0.f, 0.f, 0.f};

    for(int k0 = 0; k0 < K; k0 += 64){
        #pragma unroll
        for(int it = 0; it < 4; it++){
            int chunk = tid + it * 256;
            int row = chunk >> 3, c8 = (chunk & 7) << 3;
            s8v va;
            if constexpr (MODE == 2){
                int kk = k0 + c8;
                int he = kk >> 7, c = kk & 127;
                const short* ap = (const short*)Aptr + (size_t)(i0 + row) * 1024 + ((he >> 2) << 7) + c;
                s8v r = *(const s8v*)ap;
                float wg = gate[(size_t)(i0 + row) * 32 + he];
                #pragma unroll
                for(int j = 0; j < 8; j++) va[j] = (short)f2b(b2f(r[j]) * wg);
            } else {
                const float* ap = (const float*)Aptr + (size_t)(i0 + row) * K + k0 + c8;
                #pragma unroll
                for(int j = 0; j < 8; j++) va[j] = (short)f2b(ap[j]);
            }
            *(s8v*)&la[row * LDT + c8] = va;
            s8v vb;
            if constexpr (MODE == 0){
                const float* bp = (const float*)Bptr + (size_t)(j0 + row) * K + k0 + c8;
                #pragma unroll
                for(int j = 0; j < 8; j++) vb[j] = (short)f2b(bp[j]);
            } else {
                vb = *(const s8v*)((const short*)Bptr + (size_t)(j0 + row) * K + k0 + c8);
            }
            *(s8v*)&lb[row * LDT + c8] = vb;
        }
        __syncthreads();
        #pragma unroll
        for(int ks = 0; ks < 2; ks++){
            s8v af[4], bfr[4];
            #pragma unroll
            for(int m = 0; m < 4; m++)
                af[m] = *(const s8v*)&la[(wm + m * 16 + qr) * LDT + ks * 32 + grp * 8];
            #pragma unroll
            for(int n = 0; n < 4; n++)
                bfr[n] = *(const s8v*)&lb[(wn + n * 16 + qr) * LDT + ks * 32 + grp * 8];
            #pragma unroll
            for(int m = 0; m < 4; m++)
                #pragma unroll
                for(int n = 0; n < 4; n++)
                    acc[m][n] = __builtin_amdgcn_mfma_f32_16x16x32_bf16(af[m], bfr[n], acc[m][n], 0, 0, 0);
        }
        __syncthreads();
    }
    #pragma unroll
    for(int m = 0; m < 4; m++){
        int rb = i0 + wm + m * 16 + (grp << 2);
        #pragma unroll
        for(int n = 0; n < 4; n++){
            int col = j0 + wn + n * 16 + qr;
            #pragma unroll
            for(int r = 0; r < 4; r++){
                float val = acc[m][n][r];
                int i = rb + r;
                if constexpr (MODE == 0){
                    int h = col >> 7, c = col & 127;
                    int b = i >> 10, s = i & 1023;
                    ((short*)Cptr)[(((size_t)(b * 8 + h)) * 1024 + s) * 128 + c] = (short)f2b(val * scale);
                } else if constexpr (MODE == 1){
                    float wg = gate[(size_t)i * 32 + (col >> 7)];
                    ((short*)Cptr)[(size_t)i * 4096 + col] = (short)f2b(val * wg);
                } else {
                    ((float*)Cptr)[(size_t)i * 1024 + col] = val;
                }
            }
        }
    }
}

// ---------------- sum over E=4 experts of weighted v_allw, write V transposed [bh][c][s]
__global__ __launch_bounds__(256) void k_vreduce(const short* vallw, short* vtg){
    int bh = blockIdx.y, b = bh >> 3, h = bh & 7;
    int s0 = blockIdx.x * 32;
    constexpr int LDT = 520;
    __shared__ __align__(16) short tile[32 * LDT];
    int tid = threadIdx.x;
    #pragma unroll
    for(int p = 0; p < 8; p++){
        int chunk = tid + p * 256;
        int row = chunk >> 6, cc = (chunk & 63) << 3;
        int token = b * 1024 + s0 + row;
        *(s8v*)&tile[row * LDT + cc] = *(const s8v*)&vallw[(size_t)token * 4096 + h * 512 + cc];
    }
    __syncthreads();
    #pragma unroll
    for(int p = 0; p < 16; p++){
        int idx = tid + p * 256;
        int s = idx & 31, c = idx >> 5;
        float v = 0.f;
        #pragma unroll
        for(int e = 0; e < 4; e++) v += b2f(tile[s * LDT + e * 128 + c]);
        vtg[((size_t)bh * 128 + c) * 1024 + s0 + s] = (short)f2b(v);
    }
}

// ---------------- flash attention: 4 waves x 16 q-rows, swapped QK^T, online softmax
__global__ __launch_bounds__(256) void k_attn(const short* qg, const short* kg,
                                              const short* vtg, short* res){
    int bh = blockIdx.y, b = bh >> 3, h = bh & 7;
    int w = threadIdx.x >> 6, lane = threadIdx.x & 63;
    int q0 = blockIdx.x * 64 + w * 16;
    const short* qb = qg + (size_t)bh * 1024 * 128;
    const short* kbp = kg + (size_t)bh * 1024 * 128;
    const short* vt = vtg + (size_t)bh * 128 * 1024;
    __shared__ __align__(16) short pl_all[4][16 * 48];
    short* pl = &pl_all[w][0];
    int qr = lane & 15, grp = lane >> 4;
    s8v qf[4];
    #pragma unroll
    for(int ks = 0; ks < 4; ks++)
        qf[ks] = *(const s8v*)&qb[(size_t)(q0 + qr) * 128 + ks * 32 + grp * 8];
    f4v o[8];
    #pragma unroll
    for(int ct = 0; ct < 8; ct++) o[ct] = f4v{0.f, 0.f, 0.f, 0.f};
    float m_cur = -1e30f, l_cur = 0.f;
    for(int kb = 0; kb < 32; kb++){
        f4v s0 = {0.f,0.f,0.f,0.f}, s1 = {0.f,0.f,0.f,0.f};
        #pragma unroll
        for(int ks = 0; ks < 4; ks++){
            s8v kf0 = *(const s8v*)&kbp[(size_t)(kb * 32 + qr) * 128 + ks * 32 + grp * 8];
            s8v kf1 = *(const s8v*)&kbp[(size_t)(kb * 32 + 16 + qr) * 128 + ks * 32 + grp * 8];
            s0 = __builtin_amdgcn_mfma_f32_16x16x32_bf16(kf0, qf[ks], s0, 0, 0, 0);
            s1 = __builtin_amdgcn_mfma_f32_16x16x32_bf16(kf1, qf[ks], s1, 0, 0, 0);
        }
        float pm = s0[0];
        #pragma unroll
        for(int r = 1; r < 4; r++) pm = fmaxf(pm, s0[r]);
        #pragma unroll
        for(int r = 0; r < 4; r++) pm = fmaxf(pm, s1[r]);
        pm = fmaxf(pm, __shfl_xor(pm, 16));
        pm = fmaxf(pm, __shfl_xor(pm, 32));
        float mn = fmaxf(m_cur, pm);
        float fs = __expf(m_cur - mn);
        float p[8]; float ps = 0.f;
        #pragma unroll
        for(int r = 0; r < 4; r++){ p[r] = __expf(s0[r] - mn); ps += p[r]; }
        #pragma unroll
        for(int r = 0; r < 4; r++){ p[4 + r] = __expf(s1[r] - mn); ps += p[4 + r]; }
        ps += __shfl_xor(ps, 16);
        ps += __shfl_xor(ps, 32);
        l_cur = l_cur * fs + ps;
        m_cur = mn;
        #pragma unroll
        for(int ct = 0; ct < 8; ct++){
            o[ct][0] *= fs; o[ct][1] *= fs; o[ct][2] *= fs; o[ct][3] *= fs;
        }
        #pragma unroll
        for(int t = 0; t < 2; t++)
            #pragma unroll
            for(int r = 0; r < 4; r++)
                pl[qr * 48 + t * 16 + grp * 4 + r] = (short)f2b(p[t * 4 + r]);
        s8v pf = *(const s8v*)&pl[qr * 48 + grp * 8];
        #pragma unroll
        for(int ct = 0; ct < 8; ct++){
            s8v vf = *(const s8v*)&vt[(size_t)(ct * 16 + qr) * 1024 + kb * 32 + grp * 8];
            o[ct] = __builtin_amdgcn_mfma_f32_16x16x32_bf16(vf, pf, o[ct], 0, 0, 0);
        }
    }
    float inv = 1.0f / l_cur;
    int token = b * 1024 + q0 + qr;
    #pragma unroll
    for(int ct = 0; ct < 8; ct++){
        s4v sv;
        #pragma unroll
        for(int r = 0; r < 4; r++) sv[r] = (short)f2b(o[ct][r] * inv);
        *(s4v*)&res[(size_t)token * 1024 + h * 128 + ct * 16 + grp * 4] = sv;
    }
}

extern "C" void kernel_launch(void* const* d_in, const int* in_sizes, int n_in,
                              void* d_out, int out_size, void* d_ws, size_t ws_size,
                              hipStream_t stream){
    const float* q_src = (const float*)d_in[0];
    const float* k_src = (const float*)d_in[1];
    const float* v_src = (const float*)d_in[2];
    const float* Wq    = (const float*)d_in[3];
    const float* Wk    = (const float*)d_in[4];
    const float* Wv    = (const float*)d_in[5];
    const float* Wo    = (const float*)d_in[6];
    const float* selv  = (const float*)d_in[7];
    const float* selo  = (const float*)d_in[8];

    char* ws = (char*)d_ws;
    short* q     = (short*)(ws + 0);          // [32][1024][128] bf16  8 MB
    short* k     = (short*)(ws + 8388608);    // [32][1024][128] bf16  8 MB
    short* vt    = (short*)(ws + 16777216);   // [32][128][1024] bf16  8 MB
    short* res   = (short*)(ws + 25165824);   // [4096][1024]    bf16  8 MB
    short* wvt   = (short*)(ws + 33554432);   // [32][128][1024] bf16  8 MB
    short* wot   = (short*)(ws + 41943040);   // [1024][4096]    bf16  8 MB
    short* vallw = (short*)(ws + 50331648);   // [4096][4096]    bf16 32 MB
    float* wv    = (float*)(ws + 83886080);   // [4096][32] fp32
    float* wo    = (float*)(ws + 84410368);   // [4096][32] fp32

    const float qk_scale = 0.29730177875068026f; // 128^-0.25 applied to both q and k

    k_transpose<<<dim3(4, 32, 32), 256, 0, stream>>>(Wv, wvt, 1024, 128);
    k_transpose<<<dim3(32, 128, 1), 256, 0, stream>>>(Wo, wot, 4096, 1024);
    k_route<<<dim3(1024, 2), 256, 0, stream>>>(q_src, k_src, selv, selo, wv, wo);
    k_gemm<0><<<dim3(256), 256, 0, stream>>>(q_src, Wq, q, 4096, 1024, 1024, nullptr, qk_scale);
    k_gemm<0><<<dim3(256), 256, 0, stream>>>(k_src, Wk, k, 4096, 1024, 1024, nullptr, qk_scale);
    k_gemm<1><<<dim3(1024), 256, 0, stream>>>(v_src, wvt, vallw, 4096, 4096, 1024, wv, 1.0f);
    k_vreduce<<<dim3(32, 32), 256, 0, stream>>>(vallw, vt);
    k_attn<<<dim3(16, 32), 256, 0, stream>>>(q, k, vt, res);
    k_gemm<2><<<dim3(256), 256, 0, stream>>>(res, wot, d_out, 4096, 1024, 4096, wo, 1.0f);
}

// Round 2
// 379.127 us; speedup vs baseline: 1.3276x; 1.3276x over previous
//
#include <hip/hip_runtime.h>

#define DEV __device__ __forceinline__

typedef __attribute__((ext_vector_type(8))) short s8v;
typedef __attribute__((ext_vector_type(4))) short s4v;
typedef __attribute__((ext_vector_type(4))) float f4v;

DEV unsigned short f2b(float f){
    unsigned u = __float_as_uint(f);
    u = (u + 0x7FFFu + ((u >> 16) & 1u)) >> 16;
    return (unsigned short)u;
}
DEV float b2f(short s){ return __uint_as_float(((unsigned)(unsigned short)s) << 16); }

// async global->LDS, 16B per lane; lds base must be wave-uniform (HW adds lane*16B)
DEV void gload16(const void* g, void* l){
    __builtin_amdgcn_global_load_lds(
        (const __attribute__((address_space(1))) unsigned*)g,
        (__attribute__((address_space(3))) unsigned*)l, 16, 0, 0);
}

// B=4, S=1024, D=1024, H=8, E=4, K=2, DH=128

// ---------------- fp32 -> bf16 bulk convert: 5 buffers (3 big 4M-elem, 2 small 1M-elem)
__global__ __launch_bounds__(256) void k_cvt(const float* s0, const float* s1, const float* s2,
                                             const float* s3, const float* s4,
                                             short* o0, short* o1, short* o2, short* o3, short* o4){
    int y = blockIdx.y;
    const float* s = (y == 0) ? s0 : (y == 1) ? s1 : (y == 2) ? s2 : (y == 3) ? s3 : s4;
    short* o = (y == 0) ? o0 : (y == 1) ? o1 : (y == 2) ? o2 : (y == 3) ? o3 : o4;
    int n8 = (y < 3) ? 524288 : 131072;
    int idx = blockIdx.x * 256 + threadIdx.x;
    if(idx < n8){
        const float4* f = (const float4*)(s + (size_t)idx * 8);
        float4 a = f[0], b = f[1];
        s8v v;
        v[0] = f2b(a.x); v[1] = f2b(a.y); v[2] = f2b(a.z); v[3] = f2b(a.w);
        v[4] = f2b(b.x); v[5] = f2b(b.y); v[6] = f2b(b.z); v[7] = f2b(b.w);
        *(s8v*)(o + (size_t)idx * 8) = v;
    }
}

// ---------------- transpose (fp32 in -> bf16 out), per-z slice [R][C] -> [C][R]
__global__ __launch_bounds__(256) void k_transpose(const float* in, short* out, int R, int C){
    in  += (size_t)blockIdx.z * R * C;
    out += (size_t)blockIdx.z * R * C;
    __shared__ float t[32][33];
    int c0 = blockIdx.x * 32, r0 = blockIdx.y * 32;
    int tx = threadIdx.x & 31, ty = threadIdx.x >> 5;
    #pragma unroll
    for(int p = 0; p < 4; p++){
        int r = p * 8 + ty;
        t[r][tx] = in[(size_t)(r0 + r) * C + c0 + tx];
    }
    __syncthreads();
    #pragma unroll
    for(int p = 0; p < 4; p++){
        int c = p * 8 + ty;
        out[(size_t)(c0 + c) * R + r0 + tx] = (short)f2b(t[tx][c]);
    }
}

// ---------------- routing: sigmoid gates + top-2 of E=4 per head, fp64 accumulation
__global__ __launch_bounds__(256) void k_route(const float* qsrc, const float* ksrc,
                                               const float* selv, const float* selo,
                                               float* wvp, float* wop){
    int which = blockIdx.y;
    const float* src = which ? qsrc : ksrc;
    const float* sel = which ? selo : selv;
    float* wout = which ? wop : wvp;
    int w = threadIdx.x >> 6, lane = threadIdx.x & 63;
    int token = blockIdx.x * 4 + w;
    const float4* srow = (const float4*)(src + (size_t)token * 1024 + lane * 16);
    float x[16];
    #pragma unroll
    for(int q = 0; q < 4; q++){
        float4 v = srow[q];
        x[q*4+0] = v.x; x[q*4+1] = v.y; x[q*4+2] = v.z; x[q*4+3] = v.w;
    }
    __shared__ float gs[4][32];
    for(int e = 0; e < 32; e++){
        const float4* sr = (const float4*)(sel + (size_t)e * 1024 + lane * 16);
        double acc = 0.0;
        #pragma unroll
        for(int q = 0; q < 4; q++){
            float4 v = sr[q];
            acc += (double)x[q*4+0] * (double)v.x;
            acc += (double)x[q*4+1] * (double)v.y;
            acc += (double)x[q*4+2] * (double)v.z;
            acc += (double)x[q*4+3] * (double)v.w;
        }
        #pragma unroll
        for(int off = 1; off < 64; off <<= 1) acc += __shfl_xor(acc, off);
        if(lane == 0) gs[w][e] = 1.0f / (1.0f + expf((float)(-acc)));
    }
    if(lane < 8){
        float g[4];
        #pragma unroll
        for(int e = 0; e < 4; e++) g[e] = gs[w][lane * 4 + e];
        #pragma unroll
        for(int e = 0; e < 4; e++){
            int rank = 0;
            #pragma unroll
            for(int j = 0; j < 4; j++)
                rank += (g[j] > g[e]) || (g[j] == g[e] && j < e);
            wout[(size_t)token * 32 + lane * 4 + e] = (rank < 2) ? g[e] : 0.0f;
        }
    }
}

// ---------------- bf16 NT GEMM, 128x128 tile, BK=64, global_load_lds + 2-phase dbuf
// MODE 0: out bf16 scattered to [B,H,S,DH] * scale;  MODE 2: out fp32 row-major [M][1024]
template<int MODE>
__global__ __launch_bounds__(256) void k_gemm(const short* A, const short* Bm, void* Cptr,
                                              int K, float scale, int ntn){
    __shared__ __align__(16) short la[2][8192];
    __shared__ __align__(16) short lb[2][8192];
    int mt = blockIdx.x / ntn, nt = blockIdx.x % ntn;
    int i0 = mt << 7, j0 = nt << 7;
    int tid = threadIdx.x, lane = tid & 63, w = tid >> 6;
    int wm = (w >> 1) << 6, wn = (w & 1) << 6;
    int qr = lane & 15, grp = lane >> 4;
    int srow = lane >> 3, scol = (lane & 7) << 3;
    f4v acc[4][4];
    #pragma unroll
    for(int m = 0; m < 4; m++)
        #pragma unroll
        for(int n = 0; n < 4; n++) acc[m][n] = f4v{0.f, 0.f, 0.f, 0.f};

    int nk = K >> 6;
    #pragma unroll 1
    for(int t = -1; t < nk; t++){
        int nxt = t + 1;
        if(nxt < nk){
            int buf = nxt & 1, k0 = nxt << 6;
            #pragma unroll
            for(int it = 0; it < 4; it++){
                int seg = (w << 2) + it;
                int row = (seg << 3) + srow;
                gload16(&A[(size_t)(i0 + row) * K + k0 + scol], &la[buf][seg << 9]);
                gload16(&Bm[(size_t)(j0 + row) * K + k0 + scol], &lb[buf][seg << 9]);
            }
        }
        if(t >= 0){
            int cur = t & 1;
            #pragma unroll
            for(int ks = 0; ks < 2; ks++){
                s8v af[4], bf[4];
                #pragma unroll
                for(int m = 0; m < 4; m++)
                    af[m] = *(const s8v*)&la[cur][(wm + m * 16 + qr) * 64 + ks * 32 + grp * 8];
                #pragma unroll
                for(int n = 0; n < 4; n++)
                    bf[n] = *(const s8v*)&lb[cur][(wn + n * 16 + qr) * 64 + ks * 32 + grp * 8];
                #pragma unroll
                for(int m = 0; m < 4; m++)
                    #pragma unroll
                    for(int n = 0; n < 4; n++)
                        acc[m][n] = __builtin_amdgcn_mfma_f32_16x16x32_bf16(af[m], bf[n], acc[m][n], 0, 0, 0);
            }
        }
        __syncthreads();
    }
    #pragma unroll
    for(int m = 0; m < 4; m++){
        int rb = i0 + wm + m * 16 + (grp << 2);
        #pragma unroll
        for(int n = 0; n < 4; n++){
            int col = j0 + wn + n * 16 + qr;
            #pragma unroll
            for(int r = 0; r < 4; r++){
                float val = acc[m][n][r];
                int i = rb + r;
                if constexpr (MODE == 0){
                    int h = col >> 7, c = col & 127;
                    int b = i >> 10, s = i & 1023;
                    ((short*)Cptr)[(((size_t)(b * 8 + h)) * 1024 + s) * 128 + c] = (short)f2b(val * scale);
                } else {
                    ((float*)Cptr)[(size_t)i * 1024 + col] = val;
                }
            }
        }
    }
}

// ---------------- V projection: per (h, token-tile) block, loop E=4 experts,
// gate-weighted fp32 accumulation, write V^T [bh][c][s] bf16
__global__ __launch_bounds__(256) void k_gemmv(const short* A, const short* Bv,
                                               const float* wv, short* vt){
    __shared__ __align__(16) short la[2][8192];
    __shared__ __align__(16) short lb[2][8192];
    int h = blockIdx.x >> 5, tt = blockIdx.x & 31;
    int i0 = tt << 7;
    int tid = threadIdx.x, lane = tid & 63, w = tid >> 6;
    int wm = (w >> 1) << 6, wn = (w & 1) << 6;
    int qr = lane & 15, grp = lane >> 4;
    int srow = lane >> 3, scol = (lane & 7) << 3;
    float accr[4][4][4];
    #pragma unroll
    for(int m = 0; m < 4; m++)
        #pragma unroll
        for(int n = 0; n < 4; n++)
            #pragma unroll
            for(int r = 0; r < 4; r++) accr[m][n][r] = 0.f;

    for(int e = 0; e < 4; e++){
        const short* B = Bv + ((size_t)(h * 4 + e) << 17);
        f4v acc[4][4];
        #pragma unroll
        for(int m = 0; m < 4; m++)
            #pragma unroll
            for(int n = 0; n < 4; n++) acc[m][n] = f4v{0.f, 0.f, 0.f, 0.f};
        #pragma unroll 1
        for(int t = -1; t < 16; t++){
            int nxt = t + 1;
            if(nxt < 16){
                int buf = nxt & 1, k0 = nxt << 6;
                #pragma unroll
                for(int it = 0; it < 4; it++){
                    int seg = (w << 2) + it;
                    int row = (seg << 3) + srow;
                    gload16(&A[(size_t)(i0 + row) * 1024 + k0 + scol], &la[buf][seg << 9]);
                    gload16(&B[(size_t)row * 1024 + k0 + scol], &lb[buf][seg << 9]);
                }
            }
            if(t >= 0){
                int cur = t & 1;
                #pragma unroll
                for(int ks = 0; ks < 2; ks++){
                    s8v af[4], bf[4];
                    #pragma unroll
                    for(int m = 0; m < 4; m++)
                        af[m] = *(const s8v*)&la[cur][(wm + m * 16 + qr) * 64 + ks * 32 + grp * 8];
                    #pragma unroll
                    for(int n = 0; n < 4; n++)
                        bf[n] = *(const s8v*)&lb[cur][(wn + n * 16 + qr) * 64 + ks * 32 + grp * 8];
                    #pragma unroll
                    for(int m = 0; m < 4; m++)
                        #pragma unroll
                        for(int n = 0; n < 4; n++)
                            acc[m][n] = __builtin_amdgcn_mfma_f32_16x16x32_bf16(af[m], bf[n], acc[m][n], 0, 0, 0);
                }
            }
            __syncthreads();
        }
        #pragma unroll
        for(int m = 0; m < 4; m++){
            #pragma unroll
            for(int r = 0; r < 4; r++){
                float g = wv[(size_t)(i0 + wm + m * 16 + (grp << 2) + r) * 32 + h * 4 + e];
                #pragma unroll
                for(int n = 0; n < 4; n++) accr[m][n][r] += g * acc[m][n][r];
            }
        }
    }
    int b = i0 >> 10;
    #pragma unroll
    for(int m = 0; m < 4; m++){
        int sbase = (i0 + wm + m * 16 + (grp << 2)) & 1023;
        #pragma unroll
        for(int n = 0; n < 4; n++){
            int c = wn + n * 16 + qr;
            s4v sv;
            #pragma unroll
            for(int r = 0; r < 4; r++) sv[r] = (short)f2b(accr[m][n][r]);
            *(s4v*)&vt[(((size_t)(b * 8 + h)) * 128 + c) * 1024 + sbase] = sv;
        }
    }
}

// ---------------- flash attention: 8 waves x 16 q-rows, KVBLK=64,
// LDS-staged K/V^T (dbuf, swizzled global_load_lds), swapped QK^T, online softmax
__global__ __launch_bounds__(512) void k_attn(const short* qg, const short* kg,
                                              const short* vtg, short* res){
    __shared__ __align__(16) short lk[2][8192];   // [64 keys][128 d] swizzled
    __shared__ __align__(16) short lv[2][8192];   // [128 c][64 keys] swizzled
    __shared__ __align__(16) short pl[8][16 * 72];
    int bh = blockIdx.y, b = bh >> 3, h = bh & 7;
    int w = threadIdx.x >> 6, lane = threadIdx.x & 63;
    int qr = lane & 15, grp = lane >> 4;
    int q0 = blockIdx.x * 128 + w * 16;
    const short* qb = qg + ((size_t)bh << 17);
    const short* kb = kg + ((size_t)bh << 17);
    const short* vtb = vtg + ((size_t)bh << 17);
    short* pw = &pl[w][0];

    s8v qf[4];
    #pragma unroll
    for(int ks = 0; ks < 4; ks++)
        qf[ks] = *(const s8v*)&qb[(size_t)(q0 + qr) * 128 + ks * 32 + grp * 8];
    f4v o[8];
    #pragma unroll
    for(int ct = 0; ct < 8; ct++) o[ct] = f4v{0.f, 0.f, 0.f, 0.f};
    float m_cur = -1e30f, l_cur = 0.f;

    int klane_r = lane >> 4, klane_c = lane & 15;
    int vlane_r = lane >> 3, vlane_c = lane & 7;

    #pragma unroll 1
    for(int t = -1; t < 16; t++){
        int nxt = t + 1;
        if(nxt < 16){
            int buf = nxt & 1, kv0 = nxt << 6;
            #pragma unroll
            for(int i = 0; i < 2; i++){
                int seg = w * 2 + i;
                int kr = seg * 4 + klane_r;
                int kc = klane_c ^ (kr & 7);
                gload16(&kb[(size_t)(kv0 + kr) * 128 + kc * 8], &lk[buf][seg << 9]);
                int vr = seg * 8 + vlane_r;
                int vc = vlane_c ^ (vr & 7);
                gload16(&vtb[(size_t)vr * 1024 + kv0 + vc * 8], &lv[buf][seg << 9]);
            }
        }
        if(t >= 0){
            int cur = t & 1;
            f4v s[4];
            #pragma unroll
            for(int kt = 0; kt < 4; kt++) s[kt] = f4v{0.f, 0.f, 0.f, 0.f};
            __builtin_amdgcn_s_setprio(1);
            #pragma unroll
            for(int ks = 0; ks < 4; ks++){
                #pragma unroll
                for(int kt = 0; kt < 4; kt++){
                    int row = kt * 16 + qr;
                    s8v kf = *(const s8v*)&lk[cur][row * 128 + (((ks * 4 + grp) ^ (row & 7)) << 3)];
                    s[kt] = __builtin_amdgcn_mfma_f32_16x16x32_bf16(kf, qf[ks], s[kt], 0, 0, 0);
                }
            }
            __builtin_amdgcn_s_setprio(0);
            // online softmax over 64 keys (cols = q = qr; this lane holds 16 keys)
            float pm = s[0][0];
            #pragma unroll
            for(int kt = 0; kt < 4; kt++)
                #pragma unroll
                for(int r = 0; r < 4; r++) pm = fmaxf(pm, s[kt][r]);
            pm = fmaxf(pm, __shfl_xor(pm, 16));
            pm = fmaxf(pm, __shfl_xor(pm, 32));
            float mn = fmaxf(m_cur, pm);
            float fs = __expf(m_cur - mn);
            float ps = 0.f;
            #pragma unroll
            for(int kt = 0; kt < 4; kt++)
                #pragma unroll
                for(int r = 0; r < 4; r++){
                    s[kt][r] = __expf(s[kt][r] - mn);
                    ps += s[kt][r];
                }
            ps += __shfl_xor(ps, 16);
            ps += __shfl_xor(ps, 32);
            l_cur = l_cur * fs + ps;
            m_cur = mn;
            #pragma unroll
            for(int ct = 0; ct < 8; ct++){
                o[ct][0] *= fs; o[ct][1] *= fs; o[ct][2] *= fs; o[ct][3] *= fs;
            }
            #pragma unroll
            for(int kt = 0; kt < 4; kt++){
                s4v pv;
                #pragma unroll
                for(int r = 0; r < 4; r++) pv[r] = (short)f2b(s[kt][r]);
                *(s4v*)&pw[qr * 72 + kt * 16 + grp * 4] = pv;
            }
            s8v pf0 = *(const s8v*)&pw[qr * 72 + grp * 8];
            s8v pf1 = *(const s8v*)&pw[qr * 72 + 32 + grp * 8];
            __builtin_amdgcn_s_setprio(1);
            #pragma unroll
            for(int ct = 0; ct < 8; ct++){
                int row = ct * 16 + qr;
                s8v vf0 = *(const s8v*)&lv[cur][row * 64 + ((grp ^ (row & 7)) << 3)];
                s8v vf1 = *(const s8v*)&lv[cur][row * 64 + (((4 + grp) ^ (row & 7)) << 3)];
                o[ct] = __builtin_amdgcn_mfma_f32_16x16x32_bf16(vf0, pf0, o[ct], 0, 0, 0);
                o[ct] = __builtin_amdgcn_mfma_f32_16x16x32_bf16(vf1, pf1, o[ct], 0, 0, 0);
            }
            __builtin_amdgcn_s_setprio(0);
        }
        __syncthreads();
    }
    float inv = 1.0f / l_cur;
    int token = b * 1024 + q0 + qr;
    #pragma unroll
    for(int ct = 0; ct < 8; ct++){
        s4v sv;
        #pragma unroll
        for(int r = 0; r < 4; r++) sv[r] = (short)f2b(o[ct][r] * inv);
        *(s4v*)&res[(size_t)token * 1024 + h * 128 + ct * 16 + grp * 4] = sv;
    }
}

// ---------------- expand res [t][h*128+c] -> resw [t][(h,e)*128+c] = res * wo[t][he]
__global__ __launch_bounds__(256) void k_expand(const short* res, const float* wo, short* resw){
    int idx = blockIdx.x * 256 + threadIdx.x;     // s8v units, total 2097152
    int t = idx >> 9;
    int u = idx & 511;
    int he = u >> 4, ci = u & 15;
    int h = he >> 2;
    float g = wo[(size_t)t * 32 + he];
    s8v r = *(const s8v*)&res[(size_t)t * 1024 + h * 128 + ci * 8];
    s8v v;
    #pragma unroll
    for(int j = 0; j < 8; j++) v[j] = (short)f2b(b2f(r[j]) * g);
    *(s8v*)&resw[(size_t)t * 4096 + u * 8] = v;
}

extern "C" void kernel_launch(void* const* d_in, const int* in_sizes, int n_in,
                              void* d_out, int out_size, void* d_ws, size_t ws_size,
                              hipStream_t stream){
    const float* q_src = (const float*)d_in[0];
    const float* k_src = (const float*)d_in[1];
    const float* v_src = (const float*)d_in[2];
    const float* Wq    = (const float*)d_in[3];
    const float* Wk    = (const float*)d_in[4];
    const float* Wv    = (const float*)d_in[5];
    const float* Wo    = (const float*)d_in[6];
    const float* selv  = (const float*)d_in[7];
    const float* selo  = (const float*)d_in[8];

    const size_t MB = 1ull << 20;
    char* ws = (char*)d_ws;
    short* qsb  = (short*)(ws + 0 * MB);    // [4096][1024] bf16  8MB
    short* ksb  = (short*)(ws + 8 * MB);    // 8MB
    short* vsb  = (short*)(ws + 16 * MB);   // 8MB
    short* wqb  = (short*)(ws + 24 * MB);   // [1024][1024] bf16  2MB
    short* wkb  = (short*)(ws + 26 * MB);   // 2MB
    short* wvt  = (short*)(ws + 28 * MB);   // [32he][128][1024] bf16 8MB
    short* wot  = (short*)(ws + 36 * MB);   // [1024][4096] bf16  8MB
    short* q    = (short*)(ws + 44 * MB);   // [32bh][1024][128] bf16 8MB
    short* k    = (short*)(ws + 52 * MB);   // 8MB
    short* vt   = (short*)(ws + 60 * MB);   // [32bh][128][1024] bf16 8MB
    short* res  = (short*)(ws + 68 * MB);   // [4096][1024] bf16  8MB
    float* wv   = (float*)(ws + 76 * MB);   // [4096][32] fp32 512KB
    float* wo   = (float*)(ws + 76 * MB + 524288);
    short* resw = (short*)(ws + 0 * MB);    // [4096][4096] bf16 32MB (reuses dead qsb..wvt)

    const float qk_scale = 0.29730177875068026f; // 128^-0.25 applied to both q and k

    k_cvt<<<dim3(2048, 5), 256, 0, stream>>>(q_src, k_src, v_src, Wq, Wk, qsb, ksb, vsb, wqb, wkb);
    k_transpose<<<dim3(4, 32, 32), 256, 0, stream>>>(Wv, wvt, 1024, 128);
    k_transpose<<<dim3(32, 128, 1), 256, 0, stream>>>(Wo, wot, 4096, 1024);
    k_route<<<dim3(1024, 2), 256, 0, stream>>>(q_src, k_src, selv, selo, wv, wo);
    k_gemm<0><<<dim3(256), 256, 0, stream>>>(qsb, wqb, q, 1024, qk_scale, 8);
    k_gemm<0><<<dim3(256), 256, 0, stream>>>(ksb, wkb, k, 1024, qk_scale, 8);
    k_gemmv<<<dim3(256), 256, 0, stream>>>(vsb, wvt, wv, vt);
    k_attn<<<dim3(8, 32), 512, 0, stream>>>(q, k, vt, res);
    k_expand<<<dim3(8192), 256, 0, stream>>>(res, wo, resw);
    k_gemm<2><<<dim3(256), 256, 0, stream>>>(resw, wot, d_out, 4096, 1.0f, 8);
}

// Round 3
// 314.320 us; speedup vs baseline: 1.6013x; 1.2062x over previous
//
#include <hip/hip_runtime.h>

#define DEV __device__ __forceinline__

typedef __attribute__((ext_vector_type(8))) short s8v;
typedef __attribute__((ext_vector_type(4))) short s4v;
typedef __attribute__((ext_vector_type(4))) float f4v;

DEV unsigned short f2b(float f){
    unsigned u = __float_as_uint(f);
    u = (u + 0x7FFFu + ((u >> 16) & 1u)) >> 16;
    return (unsigned short)u;
}
DEV float b2f(short s){ return __uint_as_float(((unsigned)(unsigned short)s) << 16); }

DEV void gload16(const void* g, void* l){
    __builtin_amdgcn_global_load_lds(
        (const __attribute__((address_space(1))) unsigned*)g,
        (__attribute__((address_space(3))) unsigned*)l, 16, 0, 0);
}

// B=4, S=1024, D=1024, H=8, E=4, K=2, DH=128

// ---- shared GEMM pieces: 128x128 tile, BK=64, XOR-swizzled LDS ----
// LDS layout: lds[row][c8] = global[row][c8 ^ (row&7)] (8-elem chunks) -> 2-way banks on frag reads
DEV void stage2(const short* A, const short* B, int sA, int sB, int kA, int kB,
                short* la, short* lb, int w, int lane){
    int srow = lane >> 3;
    int swcol = ((lane & 7) ^ srow) << 3;
    #pragma unroll
    for(int it = 0; it < 4; it++){
        int seg = (w << 2) + it;
        int row = (seg << 3) + srow;
        gload16(&A[(size_t)row * sA + kA + swcol], &la[seg << 9]);
        gload16(&B[(size_t)row * sB + kB + swcol], &lb[seg << 9]);
    }
}

DEV void mfma_block(const short* la, const short* lb, int wm, int wn, int qr, int grp, f4v acc[4][4]){
    #pragma unroll
    for(int ks = 0; ks < 2; ks++){
        s8v af[4], bf[4];
        #pragma unroll
        for(int m = 0; m < 4; m++)
            af[m] = *(const s8v*)&la[(wm + m * 16 + qr) * 64 + ((((ks << 2) + grp) ^ (qr & 7)) << 3)];
        #pragma unroll
        for(int n = 0; n < 4; n++)
            bf[n] = *(const s8v*)&lb[(wn + n * 16 + qr) * 64 + ((((ks << 2) + grp) ^ (qr & 7)) << 3)];
        #pragma unroll
        for(int m = 0; m < 4; m++)
            #pragma unroll
            for(int n = 0; n < 4; n++)
                acc[m][n] = __builtin_amdgcn_mfma_f32_16x16x32_bf16(af[m], bf[n], acc[m][n], 0, 0, 0);
    }
}

// ---------------- fp32 -> bf16 bulk convert
__global__ __launch_bounds__(256) void k_cvt(const float* s0, const float* s1, const float* s2,
                                             const float* s3, const float* s4,
                                             short* o0, short* o1, short* o2, short* o3, short* o4){
    int y = blockIdx.y;
    const float* s = (y == 0) ? s0 : (y == 1) ? s1 : (y == 2) ? s2 : (y == 3) ? s3 : s4;
    short* o = (y == 0) ? o0 : (y == 1) ? o1 : (y == 2) ? o2 : (y == 3) ? o3 : o4;
    int n8 = (y < 3) ? 524288 : 131072;
    int idx = blockIdx.x * 256 + threadIdx.x;
    if(idx < n8){
        const float4* f = (const float4*)(s + (size_t)idx * 8);
        float4 a = f[0], b = f[1];
        s8v v;
        v[0] = f2b(a.x); v[1] = f2b(a.y); v[2] = f2b(a.z); v[3] = f2b(a.w);
        v[4] = f2b(b.x); v[5] = f2b(b.y); v[6] = f2b(b.z); v[7] = f2b(b.w);
        *(s8v*)(o + (size_t)idx * 8) = v;
    }
}

// ---------------- transpose (fp32 in -> bf16 out), per-z slice [R][C] -> [C][R]
__global__ __launch_bounds__(256) void k_transpose(const float* in, short* out, int R, int C){
    in  += (size_t)blockIdx.z * R * C;
    out += (size_t)blockIdx.z * R * C;
    __shared__ float t[32][33];
    int c0 = blockIdx.x * 32, r0 = blockIdx.y * 32;
    int tx = threadIdx.x & 31, ty = threadIdx.x >> 5;
    #pragma unroll
    for(int p = 0; p < 4; p++){
        int r = p * 8 + ty;
        t[r][tx] = in[(size_t)(r0 + r) * C + c0 + tx];
    }
    __syncthreads();
    #pragma unroll
    for(int p = 0; p < 4; p++){
        int c = p * 8 + ty;
        out[(size_t)(c0 + c) * R + r0 + tx] = (short)f2b(t[tx][c]);
    }
}

// ---------------- routing: sigmoid gates + top-2 of E=4 per head, fp64 accumulation
__global__ __launch_bounds__(256) void k_route(const float* qsrc, const float* ksrc,
                                               const float* selv, const float* selo,
                                               float* wvp, float* wop){
    int which = blockIdx.y;
    const float* src = which ? qsrc : ksrc;
    const float* sel = which ? selo : selv;
    float* wout = which ? wop : wvp;
    int w = threadIdx.x >> 6, lane = threadIdx.x & 63;
    int token = blockIdx.x * 4 + w;
    const float4* srow = (const float4*)(src + (size_t)token * 1024 + lane * 16);
    float x[16];
    #pragma unroll
    for(int q = 0; q < 4; q++){
        float4 v = srow[q];
        x[q*4+0] = v.x; x[q*4+1] = v.y; x[q*4+2] = v.z; x[q*4+3] = v.w;
    }
    __shared__ float gs[4][32];
    for(int e = 0; e < 32; e++){
        const float4* sr = (const float4*)(sel + (size_t)e * 1024 + lane * 16);
        double acc = 0.0;
        #pragma unroll
        for(int q = 0; q < 4; q++){
            float4 v = sr[q];
            acc += (double)x[q*4+0] * (double)v.x;
            acc += (double)x[q*4+1] * (double)v.y;
            acc += (double)x[q*4+2] * (double)v.z;
            acc += (double)x[q*4+3] * (double)v.w;
        }
        #pragma unroll
        for(int off = 1; off < 64; off <<= 1) acc += __shfl_xor(acc, off);
        if(lane == 0) gs[w][e] = 1.0f / (1.0f + expf((float)(-acc)));
    }
    if(lane < 8){
        float g[4];
        #pragma unroll
        for(int e = 0; e < 4; e++) g[e] = gs[w][lane * 4 + e];
        #pragma unroll
        for(int e = 0; e < 4; e++){
            int rank = 0;
            #pragma unroll
            for(int j = 0; j < 4; j++)
                rank += (g[j] > g[e]) || (g[j] == g[e] && j < e);
            wout[(size_t)token * 32 + lane * 4 + e] = (rank < 2) ? g[e] : 0.0f;
        }
    }
}

// ---------------- fused Q+K projection GEMM: grid 512 (2 blocks/CU), XCD swizzle
__global__ __launch_bounds__(256) void k_gemmqk(const short* qsb, const short* ksb,
                                                const short* wqb, const short* wkb,
                                                short* qo, short* ko, float scale){
    __shared__ __align__(16) short la[2][8192];
    __shared__ __align__(16) short lb[2][8192];
    int wg = (blockIdx.x & 7) * 64 + (blockIdx.x >> 3);
    int which = wg >> 8, tl = wg & 255;
    int mt = tl >> 3, nt = tl & 7;
    const short* A = (which ? ksb : qsb) + ((size_t)(mt << 7)) * 1024;
    const short* B = (which ? wkb : wqb) + ((size_t)(nt << 7)) * 1024;
    short* out = which ? ko : qo;
    int tid = threadIdx.x, lane = tid & 63, w = tid >> 6;
    int wm = (w >> 1) << 6, wn = (w & 1) << 6;
    int qr = lane & 15, grp = lane >> 4;
    f4v acc[4][4];
    #pragma unroll
    for(int m = 0; m < 4; m++)
        #pragma unroll
        for(int n = 0; n < 4; n++) acc[m][n] = f4v{0.f, 0.f, 0.f, 0.f};
    #pragma unroll 1
    for(int t = -1; t < 16; t++){
        int nxt = t + 1;
        if(nxt < 16)
            stage2(A, B, 1024, 1024, nxt << 6, nxt << 6, la[nxt & 1], lb[nxt & 1], w, lane);
        if(t >= 0)
            mfma_block(la[t & 1], lb[t & 1], wm, wn, qr, grp, acc);
        __syncthreads();
    }
    #pragma unroll
    for(int m = 0; m < 4; m++){
        int rb = (mt << 7) + wm + m * 16 + (grp << 2);
        #pragma unroll
        for(int n = 0; n < 4; n++){
            int col = (nt << 7) + wn + n * 16 + qr;
            int h = col >> 7, c = col & 127;
            #pragma unroll
            for(int r = 0; r < 4; r++){
                int i = rb + r, b = i >> 10, s = i & 1023;
                out[(((size_t)(b * 8 + h)) * 1024 + s) * 128 + c] = (short)f2b(acc[m][n][r] * scale);
            }
        }
    }
}

// ---------------- V projection: grid 512 = (h, token-tile, expert-pair), gated fp32 partials
__global__ __launch_bounds__(256) void k_gemmv(const short* vsb, const short* wvt,
                                               const float* wv, float* pv){
    __shared__ __align__(16) short la[2][8192];
    __shared__ __align__(16) short lb[2][8192];
    int wg = (blockIdx.x & 7) * 64 + (blockIdx.x >> 3);
    int h = wg >> 6, rest = wg & 63, tt = rest >> 1, ep = rest & 1;
    int i0 = tt << 7;
    const short* A = vsb + (size_t)i0 * 1024;
    int tid = threadIdx.x, lane = tid & 63, w = tid >> 6;
    int wm = (w >> 1) << 6, wn = (w & 1) << 6;
    int qr = lane & 15, grp = lane >> 4;
    float accr[4][4][4];
    f4v acc[4][4];
    #pragma unroll
    for(int m = 0; m < 4; m++)
        #pragma unroll
        for(int n = 0; n < 4; n++){
            acc[m][n] = f4v{0.f, 0.f, 0.f, 0.f};
            #pragma unroll
            for(int r = 0; r < 4; r++) accr[m][n][r] = 0.f;
        }
    #pragma unroll 1
    for(int t = -1; t < 32; t++){
        int nxt = t + 1;
        if(nxt < 32){
            int he = h * 4 + ep * 2 + (nxt >> 4);
            const short* B = wvt + ((size_t)he << 17);
            stage2(A, B, 1024, 1024, (nxt & 15) << 6, (nxt & 15) << 6, la[nxt & 1], lb[nxt & 1], w, lane);
        }
        if(t >= 0){
            mfma_block(la[t & 1], lb[t & 1], wm, wn, qr, grp, acc);
            if((t & 15) == 15){
                int he = h * 4 + ep * 2 + (t >> 4);
                #pragma unroll
                for(int m = 0; m < 4; m++){
                    #pragma unroll
                    for(int r = 0; r < 4; r++){
                        float g = wv[(size_t)(i0 + wm + m * 16 + (grp << 2) + r) * 32 + he];
                        #pragma unroll
                        for(int n = 0; n < 4; n++){
                            accr[m][n][r] += g * acc[m][n][r];
                            acc[m][n][r] = 0.f;
                        }
                    }
                }
            }
        }
        __syncthreads();
    }
    int b = i0 >> 10;
    int bh = b * 8 + h;
    #pragma unroll
    for(int m = 0; m < 4; m++){
        int sbase = (i0 + wm + m * 16 + (grp << 2)) & 1023;
        #pragma unroll
        for(int n = 0; n < 4; n++){
            int c = wn + n * 16 + qr;
            f4v st;
            #pragma unroll
            for(int r = 0; r < 4; r++) st[r] = accr[m][n][r];
            *(f4v*)&pv[((size_t)(ep * 32 + bh) * 128 + c) * 1024 + sbase] = st;
        }
    }
}

// ---------------- O projection: grid 512 = (tile, K-half), fp32 partials
__global__ __launch_bounds__(256) void k_gemmo(const short* resw, const short* wot, float* po){
    __shared__ __align__(16) short la[2][8192];
    __shared__ __align__(16) short lb[2][8192];
    int wg = (blockIdx.x & 7) * 64 + (blockIdx.x >> 3);
    int ksp = wg & 1, tile = wg >> 1;
    int mt = tile >> 3, nt = tile & 7;
    const short* A = resw + (size_t)(mt << 7) * 4096 + ksp * 2048;
    const short* B = wot + (size_t)(nt << 7) * 4096 + ksp * 2048;
    int tid = threadIdx.x, lane = tid & 63, w = tid >> 6;
    int wm = (w >> 1) << 6, wn = (w & 1) << 6;
    int qr = lane & 15, grp = lane >> 4;
    f4v acc[4][4];
    #pragma unroll
    for(int m = 0; m < 4; m++)
        #pragma unroll
        for(int n = 0; n < 4; n++) acc[m][n] = f4v{0.f, 0.f, 0.f, 0.f};
    #pragma unroll 1
    for(int t = -1; t < 32; t++){
        int nxt = t + 1;
        if(nxt < 32)
            stage2(A, B, 4096, 4096, nxt << 6, nxt << 6, la[nxt & 1], lb[nxt & 1], w, lane);
        if(t >= 0)
            mfma_block(la[t & 1], lb[t & 1], wm, wn, qr, grp, acc);
        __syncthreads();
    }
    po += (size_t)ksp * 4194304;
    #pragma unroll
    for(int m = 0; m < 4; m++){
        int rb = (mt << 7) + wm + m * 16 + (grp << 2);
        #pragma unroll
        for(int n = 0; n < 4; n++){
            int col = (nt << 7) + wn + n * 16 + qr;
            #pragma unroll
            for(int r = 0; r < 4; r++)
                po[(size_t)(rb + r) * 1024 + col] = acc[m][n][r];
        }
    }
}

// ---------------- partial reduce: out = p0 + p1 (bf16 or fp32 out), 4M elems
template<int BF>
__global__ __launch_bounds__(256) void k_red(const float* p0, const float* p1, void* out){
    size_t idx = ((size_t)blockIdx.x * 256 + threadIdx.x) * 4;
    f4v a = *(const f4v*)&p0[idx];
    f4v b = *(const f4v*)&p1[idx];
    f4v s = a + b;
    if(BF){
        s4v v;
        #pragma unroll
        for(int r = 0; r < 4; r++) v[r] = (short)f2b(s[r]);
        *(s4v*)((short*)out + idx) = v;
    } else {
        *(f4v*)((float*)out + idx) = s;
    }
}

// ---------------- flash attention: 8 waves x 16 q-rows, KVBLK=64 (unchanged from R2)
__global__ __launch_bounds__(512) void k_attn(const short* qg, const short* kg,
                                              const short* vtg, short* res){
    __shared__ __align__(16) short lk[2][8192];
    __shared__ __align__(16) short lv[2][8192];
    __shared__ __align__(16) short pl[8][16 * 72];
    int bh = blockIdx.y, b = bh >> 3, h = bh & 7;
    int w = threadIdx.x >> 6, lane = threadIdx.x & 63;
    int qr = lane & 15, grp = lane >> 4;
    int q0 = blockIdx.x * 128 + w * 16;
    const short* qb = qg + ((size_t)bh << 17);
    const short* kb = kg + ((size_t)bh << 17);
    const short* vtb = vtg + ((size_t)bh << 17);
    short* pw = &pl[w][0];

    s8v qf[4];
    #pragma unroll
    for(int ks = 0; ks < 4; ks++)
        qf[ks] = *(const s8v*)&qb[(size_t)(q0 + qr) * 128 + ks * 32 + grp * 8];
    f4v o[8];
    #pragma unroll
    for(int ct = 0; ct < 8; ct++) o[ct] = f4v{0.f, 0.f, 0.f, 0.f};
    float m_cur = -1e30f, l_cur = 0.f;

    int klane_r = lane >> 4, klane_c = lane & 15;
    int vlane_r = lane >> 3, vlane_c = lane & 7;

    #pragma unroll 1
    for(int t = -1; t < 16; t++){
        int nxt = t + 1;
        if(nxt < 16){
            int buf = nxt & 1, kv0 = nxt << 6;
            #pragma unroll
            for(int i = 0; i < 2; i++){
                int seg = w * 2 + i;
                int kr = seg * 4 + klane_r;
                int kc = klane_c ^ (kr & 7);
                gload16(&kb[(size_t)(kv0 + kr) * 128 + kc * 8], &lk[buf][seg << 9]);
                int vr = seg * 8 + vlane_r;
                int vc = vlane_c ^ (vr & 7);
                gload16(&vtb[(size_t)vr * 1024 + kv0 + vc * 8], &lv[buf][seg << 9]);
            }
        }
        if(t >= 0){
            int cur = t & 1;
            f4v s[4];
            #pragma unroll
            for(int kt = 0; kt < 4; kt++) s[kt] = f4v{0.f, 0.f, 0.f, 0.f};
            __builtin_amdgcn_s_setprio(1);
            #pragma unroll
            for(int ks = 0; ks < 4; ks++){
                #pragma unroll
                for(int kt = 0; kt < 4; kt++){
                    int row = kt * 16 + qr;
                    s8v kf = *(const s8v*)&lk[cur][row * 128 + (((ks * 4 + grp) ^ (row & 7)) << 3)];
                    s[kt] = __builtin_amdgcn_mfma_f32_16x16x32_bf16(kf, qf[ks], s[kt], 0, 0, 0);
                }
            }
            __builtin_amdgcn_s_setprio(0);
            float pm = s[0][0];
            #pragma unroll
            for(int kt = 0; kt < 4; kt++)
                #pragma unroll
                for(int r = 0; r < 4; r++) pm = fmaxf(pm, s[kt][r]);
            pm = fmaxf(pm, __shfl_xor(pm, 16));
            pm = fmaxf(pm, __shfl_xor(pm, 32));
            float mn = fmaxf(m_cur, pm);
            float fs = __expf(m_cur - mn);
            float ps = 0.f;
            #pragma unroll
            for(int kt = 0; kt < 4; kt++)
                #pragma unroll
                for(int r = 0; r < 4; r++){
                    s[kt][r] = __expf(s[kt][r] - mn);
                    ps += s[kt][r];
                }
            ps += __shfl_xor(ps, 16);
            ps += __shfl_xor(ps, 32);
            l_cur = l_cur * fs + ps;
            m_cur = mn;
            #pragma unroll
            for(int ct = 0; ct < 8; ct++){
                o[ct][0] *= fs; o[ct][1] *= fs; o[ct][2] *= fs; o[ct][3] *= fs;
            }
            #pragma unroll
            for(int kt = 0; kt < 4; kt++){
                s4v pvv;
                #pragma unroll
                for(int r = 0; r < 4; r++) pvv[r] = (short)f2b(s[kt][r]);
                *(s4v*)&pw[qr * 72 + kt * 16 + grp * 4] = pvv;
            }
            s8v pf0 = *(const s8v*)&pw[qr * 72 + grp * 8];
            s8v pf1 = *(const s8v*)&pw[qr * 72 + 32 + grp * 8];
            __builtin_amdgcn_s_setprio(1);
            #pragma unroll
            for(int ct = 0; ct < 8; ct++){
                int row = ct * 16 + qr;
                s8v vf0 = *(const s8v*)&lv[cur][row * 64 + ((grp ^ (row & 7)) << 3)];
                s8v vf1 = *(const s8v*)&lv[cur][row * 64 + (((4 + grp) ^ (row & 7)) << 3)];
                o[ct] = __builtin_amdgcn_mfma_f32_16x16x32_bf16(vf0, pf0, o[ct], 0, 0, 0);
                o[ct] = __builtin_amdgcn_mfma_f32_16x16x32_bf16(vf1, pf1, o[ct], 0, 0, 0);
            }
            __builtin_amdgcn_s_setprio(0);
        }
        __syncthreads();
    }
    float inv = 1.0f / l_cur;
    int token = b * 1024 + q0 + qr;
    #pragma unroll
    for(int ct = 0; ct < 8; ct++){
        s4v sv;
        #pragma unroll
        for(int r = 0; r < 4; r++) sv[r] = (short)f2b(o[ct][r] * inv);
        *(s4v*)&res[(size_t)token * 1024 + h * 128 + ct * 16 + grp * 4] = sv;
    }
}

// ---------------- expand res [t][h*128+c] -> resw [t][(h,e)*128+c] = res * wo[t][he]
__global__ __launch_bounds__(256) void k_expand(const short* res, const float* wo, short* resw){
    int idx = blockIdx.x * 256 + threadIdx.x;
    int t = idx >> 9;
    int u = idx & 511;
    int he = u >> 4, ci = u & 15;
    int h = he >> 2;
    float g = wo[(size_t)t * 32 + he];
    s8v r = *(const s8v*)&res[(size_t)t * 1024 + h * 128 + ci * 8];
    s8v v;
    #pragma unroll
    for(int j = 0; j < 8; j++) v[j] = (short)f2b(b2f(r[j]) * g);
    *(s8v*)&resw[(size_t)t * 4096 + u * 8] = v;
}

extern "C" void kernel_launch(void* const* d_in, const int* in_sizes, int n_in,
                              void* d_out, int out_size, void* d_ws, size_t ws_size,
                              hipStream_t stream){
    const float* q_src = (const float*)d_in[0];
    const float* k_src = (const float*)d_in[1];
    const float* v_src = (const float*)d_in[2];
    const float* Wq    = (const float*)d_in[3];
    const float* Wk    = (const float*)d_in[4];
    const float* Wv    = (const float*)d_in[5];
    const float* Wo    = (const float*)d_in[6];
    const float* selv  = (const float*)d_in[7];
    const float* selo  = (const float*)d_in[8];

    const size_t MB = 1ull << 20;
    char* ws = (char*)d_ws;
    short* qsb  = (short*)(ws + 0 * MB);    // [4096][1024] bf16  8MB (dead after qk gemm)
    short* ksb  = (short*)(ws + 8 * MB);    // 8MB
    short* vsb  = (short*)(ws + 16 * MB);   // 8MB (dead after v gemm)
    short* wqb  = (short*)(ws + 24 * MB);   // 2MB
    short* wkb  = (short*)(ws + 26 * MB);   // 2MB
    short* wvt  = (short*)(ws + 28 * MB);   // [32he][128][1024] 8MB (dead after v gemm)
    short* wot  = (short*)(ws + 36 * MB);   // [1024][4096] 8MB (live until o gemm)
    short* q    = (short*)(ws + 44 * MB);   // [32bh][1024][128] 8MB
    short* k    = (short*)(ws + 52 * MB);   // 8MB
    short* vt   = (short*)(ws + 60 * MB);   // [32bh][128][1024] 8MB
    short* res  = (short*)(ws + 68 * MB);   // [4096][1024] 8MB
    float* wv   = (float*)(ws + 76 * MB);   // [4096][32] 512KB
    float* wo   = (float*)(ws + 76 * MB + 524288);
    float* pv   = (float*)(ws + 80 * MB);   // [2][32][128][1024] fp32 32MB (dead after vred)
    float* po   = (float*)(ws + 80 * MB);   // [2][4096][1024] fp32 32MB (reuses pv)
    short* resw = (short*)(ws + 0 * MB);    // [4096][4096] 32MB (reuses qsb..wvt region)

    const float qk_scale = 0.29730177875068026f; // 128^-0.25 applied to both q and k

    k_cvt<<<dim3(2048, 5), 256, 0, stream>>>(q_src, k_src, v_src, Wq, Wk, qsb, ksb, vsb, wqb, wkb);
    k_transpose<<<dim3(4, 32, 32), 256, 0, stream>>>(Wv, wvt, 1024, 128);
    k_transpose<<<dim3(32, 128, 1), 256, 0, stream>>>(Wo, wot, 4096, 1024);
    k_route<<<dim3(1024, 2), 256, 0, stream>>>(q_src, k_src, selv, selo, wv, wo);
    k_gemmqk<<<dim3(512), 256, 0, stream>>>(qsb, ksb, wqb, wkb, q, k, qk_scale);
    k_gemmv<<<dim3(512), 256, 0, stream>>>(vsb, wvt, wv, pv);
    k_red<1><<<dim3(4096), 256, 0, stream>>>(pv, pv + 4194304, vt);
    k_attn<<<dim3(8, 32), 512, 0, stream>>>(q, k, vt, res);
    k_expand<<<dim3(8192), 256, 0, stream>>>(res, wo, resw);
    k_gemmo<<<dim3(512), 256, 0, stream>>>(resw, wot, po);
    k_red<0><<<dim3(4096), 256, 0, stream>>>(po, po + 4194304, (float*)d_out);
}

// Round 4
// 264.840 us; speedup vs baseline: 1.9004x; 1.1868x over previous
//
#include <hip/hip_runtime.h>

#define DEV __device__ __forceinline__

typedef __attribute__((ext_vector_type(8))) short s8v;
typedef __attribute__((ext_vector_type(4))) short s4v;
typedef __attribute__((ext_vector_type(4))) float f4v;

DEV unsigned short f2b(float f){
    unsigned u = __float_as_uint(f);
    u = (u + 0x7FFFu + ((u >> 16) & 1u)) >> 16;
    return (unsigned short)u;
}
DEV float b2f(short s){ return __uint_as_float(((unsigned)(unsigned short)s) << 16); }

DEV void gload16(const void* g, void* l){
    __builtin_amdgcn_global_load_lds(
        (const __attribute__((address_space(1))) unsigned*)g,
        (__attribute__((address_space(3))) unsigned*)l, 16, 0, 0);
}

// B=4, S=1024, D=1024, H=8, E=4, K=2, DH=128

// ---- shared GEMM pieces: 128x128 tile, BK=64, XOR-swizzled LDS ----
DEV void stage2(const short* A, const short* B, int sA, int sB, int kA, int kB,
                short* la, short* lb, int w, int lane){
    int srow = lane >> 3;
    int swcol = ((lane & 7) ^ srow) << 3;
    #pragma unroll
    for(int it = 0; it < 4; it++){
        int seg = (w << 2) + it;
        int row = (seg << 3) + srow;
        gload16(&A[(size_t)row * sA + kA + swcol], &la[seg << 9]);
        gload16(&B[(size_t)row * sB + kB + swcol], &lb[seg << 9]);
    }
}

DEV void mfma_block(const short* la, const short* lb, int wm, int wn, int qr, int grp, f4v acc[4][4]){
    #pragma unroll
    for(int ks = 0; ks < 2; ks++){
        s8v af[4], bf[4];
        #pragma unroll
        for(int m = 0; m < 4; m++)
            af[m] = *(const s8v*)&la[(wm + m * 16 + qr) * 64 + ((((ks << 2) + grp) ^ (qr & 7)) << 3)];
        #pragma unroll
        for(int n = 0; n < 4; n++)
            bf[n] = *(const s8v*)&lb[(wn + n * 16 + qr) * 64 + ((((ks << 2) + grp) ^ (qr & 7)) << 3)];
        #pragma unroll
        for(int m = 0; m < 4; m++)
            #pragma unroll
            for(int n = 0; n < 4; n++)
                acc[m][n] = __builtin_amdgcn_mfma_f32_16x16x32_bf16(af[m], bf[n], acc[m][n], 0, 0, 0);
    }
}

// ---------------- fp32 -> bf16 bulk convert
__global__ __launch_bounds__(256) void k_cvt(const float* s0, const float* s1, const float* s2,
                                             const float* s3, const float* s4,
                                             short* o0, short* o1, short* o2, short* o3, short* o4){
    int y = blockIdx.y;
    const float* s = (y == 0) ? s0 : (y == 1) ? s1 : (y == 2) ? s2 : (y == 3) ? s3 : s4;
    short* o = (y == 0) ? o0 : (y == 1) ? o1 : (y == 2) ? o2 : (y == 3) ? o3 : o4;
    int n8 = (y < 3) ? 524288 : 131072;
    int idx = blockIdx.x * 256 + threadIdx.x;
    if(idx < n8){
        const float4* f = (const float4*)(s + (size_t)idx * 8);
        float4 a = f[0], b = f[1];
        s8v v;
        v[0] = f2b(a.x); v[1] = f2b(a.y); v[2] = f2b(a.z); v[3] = f2b(a.w);
        v[4] = f2b(b.x); v[5] = f2b(b.y); v[6] = f2b(b.z); v[7] = f2b(b.w);
        *(s8v*)(o + (size_t)idx * 8) = v;
    }
}

// ---------------- transpose (fp32 in -> bf16 out), per-z slice [R][C] -> [C][R]
__global__ __launch_bounds__(256) void k_transpose(const float* in, short* out, int R, int C){
    in  += (size_t)blockIdx.z * R * C;
    out += (size_t)blockIdx.z * R * C;
    __shared__ float t[32][33];
    int c0 = blockIdx.x * 32, r0 = blockIdx.y * 32;
    int tx = threadIdx.x & 31, ty = threadIdx.x >> 5;
    #pragma unroll
    for(int p = 0; p < 4; p++){
        int r = p * 8 + ty;
        t[r][tx] = in[(size_t)(r0 + r) * C + c0 + tx];
    }
    __syncthreads();
    #pragma unroll
    for(int p = 0; p < 4; p++){
        int c = p * 8 + ty;
        out[(size_t)(c0 + c) * R + r0 + tx] = (short)f2b(t[tx][c]);
    }
}

// ---------------- routing: sigmoid gates + top-2 of E=4 per head, fp32
__global__ __launch_bounds__(256) void k_route(const float* qsrc, const float* ksrc,
                                               const float* selv, const float* selo,
                                               float* wvp, float* wop){
    int which = blockIdx.y;
    const float* src = which ? qsrc : ksrc;
    const float* sel = which ? selo : selv;
    float* wout = which ? wop : wvp;
    int w = threadIdx.x >> 6, lane = threadIdx.x & 63;
    int token = blockIdx.x * 4 + w;
    const float4* srow = (const float4*)(src + (size_t)token * 1024 + lane * 16);
    float x[16];
    #pragma unroll
    for(int q = 0; q < 4; q++){
        float4 v = srow[q];
        x[q*4+0] = v.x; x[q*4+1] = v.y; x[q*4+2] = v.z; x[q*4+3] = v.w;
    }
    __shared__ float gs[4][32];
    for(int e = 0; e < 32; e++){
        const float4* sr = (const float4*)(sel + (size_t)e * 1024 + lane * 16);
        float acc = 0.f;
        #pragma unroll
        for(int q = 0; q < 4; q++){
            float4 v = sr[q];
            acc = fmaf(x[q*4+0], v.x, acc);
            acc = fmaf(x[q*4+1], v.y, acc);
            acc = fmaf(x[q*4+2], v.z, acc);
            acc = fmaf(x[q*4+3], v.w, acc);
        }
        #pragma unroll
        for(int off = 1; off < 64; off <<= 1) acc += __shfl_xor(acc, off);
        if(lane == 0) gs[w][e] = 1.0f / (1.0f + expf(-acc));
    }
    if(lane < 8){
        float g[4];
        #pragma unroll
        for(int e = 0; e < 4; e++) g[e] = gs[w][lane * 4 + e];
        #pragma unroll
        for(int e = 0; e < 4; e++){
            int rank = 0;
            #pragma unroll
            for(int j = 0; j < 4; j++)
                rank += (g[j] > g[e]) || (g[j] == g[e] && j < e);
            wout[(size_t)token * 32 + lane * 4 + e] = (rank < 2) ? g[e] : 0.0f;
        }
    }
}

// ---------------- fused Q+K projection GEMM: grid 512, natural-layout output [4096][1024]
__global__ __launch_bounds__(256) void k_gemmqk(const short* qsb, const short* ksb,
                                                const short* wqb, const short* wkb,
                                                short* qo, short* ko, float scale){
    __shared__ __align__(16) short la[2][8192];
    __shared__ __align__(16) short lb[2][8192];
    int wg = (blockIdx.x & 7) * 64 + (blockIdx.x >> 3);
    int which = wg >> 8, tl = wg & 255;
    int mt = tl >> 3, nt = tl & 7;
    const short* A = (which ? ksb : qsb) + ((size_t)(mt << 7)) * 1024;
    const short* B = (which ? wkb : wqb) + ((size_t)(nt << 7)) * 1024;
    short* out = which ? ko : qo;
    int tid = threadIdx.x, lane = tid & 63, w = tid >> 6;
    int wm = (w >> 1) << 6, wn = (w & 1) << 6;
    int qr = lane & 15, grp = lane >> 4;
    f4v acc[4][4];
    #pragma unroll
    for(int m = 0; m < 4; m++)
        #pragma unroll
        for(int n = 0; n < 4; n++) acc[m][n] = f4v{0.f, 0.f, 0.f, 0.f};
    #pragma unroll 1
    for(int t = -1; t < 16; t++){
        int nxt = t + 1;
        if(nxt < 16)
            stage2(A, B, 1024, 1024, nxt << 6, nxt << 6, la[nxt & 1], lb[nxt & 1], w, lane);
        if(t >= 0)
            mfma_block(la[t & 1], lb[t & 1], wm, wn, qr, grp, acc);
        __syncthreads();
    }
    #pragma unroll
    for(int m = 0; m < 4; m++){
        int rb = (mt << 7) + wm + m * 16 + (grp << 2);
        #pragma unroll
        for(int n = 0; n < 4; n++){
            int col = (nt << 7) + wn + n * 16 + qr;
            #pragma unroll
            for(int r = 0; r < 4; r++)
                out[(size_t)(rb + r) * 1024 + col] = (short)f2b(acc[m][n][r] * scale);
        }
    }
}

// ---------------- dense v_all GEMM: [4096 tok][1024] x [4096 (he,c)][1024]^T -> [4096][4096]
// grid 1024, single-buffer 32KB (m97 regime, 3+ blocks/CU), XCD swizzle
__global__ __launch_bounds__(256) void k_gemmva(const short* A, const short* B, short* C){
    __shared__ __align__(16) short la[8192];
    __shared__ __align__(16) short lb[8192];
    int wg = (blockIdx.x & 7) * 128 + (blockIdx.x >> 3);
    int mt = wg >> 5, nt = wg & 31;
    int i0 = mt << 7, j0 = nt << 7;
    const short* Ab = A + (size_t)i0 * 1024;
    const short* Bb = B + (size_t)j0 * 1024;
    int tid = threadIdx.x, lane = tid & 63, w = tid >> 6;
    int wm = (w >> 1) << 6, wn = (w & 1) << 6;
    int qr = lane & 15, grp = lane >> 4;
    f4v acc[4][4];
    #pragma unroll
    for(int m = 0; m < 4; m++)
        #pragma unroll
        for(int n = 0; n < 4; n++) acc[m][n] = f4v{0.f, 0.f, 0.f, 0.f};
    #pragma unroll 1
    for(int t = 0; t < 16; t++){
        stage2(Ab, Bb, 1024, 1024, t << 6, t << 6, la, lb, w, lane);
        __syncthreads();
        mfma_block(la, lb, wm, wn, qr, grp, acc);
        __syncthreads();
    }
    #pragma unroll
    for(int m = 0; m < 4; m++){
        int rb = i0 + wm + m * 16 + (grp << 2);
        #pragma unroll
        for(int n = 0; n < 4; n++){
            int col = j0 + wn + n * 16 + qr;
            #pragma unroll
            for(int r = 0; r < 4; r++)
                C[(size_t)(rb + r) * 4096 + col] = (short)f2b(acc[m][n][r]);
        }
    }
}

// ---------------- gated reduce over E=4 + transpose: vall -> vt [bh][c][s]
__global__ __launch_bounds__(256) void k_vredg(const short* vall, const float* wv, short* vtg){
    int bh = blockIdx.y, b = bh >> 3, h = bh & 7;
    int s0 = blockIdx.x * 32;
    constexpr int LDT = 520;
    __shared__ __align__(16) short tile[32 * LDT];
    __shared__ float gsm[32][4];
    int tid = threadIdx.x;
    #pragma unroll
    for(int p = 0; p < 8; p++){
        int chunk = tid + p * 256;
        int row = chunk >> 6, cc = (chunk & 63) << 3;
        int token = b * 1024 + s0 + row;
        *(s8v*)&tile[row * LDT + cc] = *(const s8v*)&vall[(size_t)token * 4096 + h * 512 + cc];
    }
    if(tid < 128){
        int row = tid >> 2, e = tid & 3;
        gsm[row][e] = wv[(size_t)(b * 1024 + s0 + row) * 32 + h * 4 + e];
    }
    __syncthreads();
    #pragma unroll
    for(int p = 0; p < 16; p++){
        int idx = tid + p * 256;
        int s = idx & 31, c = idx >> 5;
        float v = 0.f;
        #pragma unroll
        for(int e = 0; e < 4; e++) v += b2f(tile[s * LDT + e * 128 + c]) * gsm[s][e];
        vtg[((size_t)bh * 128 + c) * 1024 + s0 + s] = (short)f2b(v);
    }
}

// ---------------- O projection: grid 512 = (tile, K-half), fp32 partials
__global__ __launch_bounds__(256) void k_gemmo(const short* resw, const short* wot, float* po){
    __shared__ __align__(16) short la[2][8192];
    __shared__ __align__(16) short lb[2][8192];
    int wg = (blockIdx.x & 7) * 64 + (blockIdx.x >> 3);
    int ksp = wg & 1, tile = wg >> 1;
    int mt = tile >> 3, nt = tile & 7;
    const short* A = resw + (size_t)(mt << 7) * 4096 + ksp * 2048;
    const short* B = wot + (size_t)(nt << 7) * 4096 + ksp * 2048;
    int tid = threadIdx.x, lane = tid & 63, w = tid >> 6;
    int wm = (w >> 1) << 6, wn = (w & 1) << 6;
    int qr = lane & 15, grp = lane >> 4;
    f4v acc[4][4];
    #pragma unroll
    for(int m = 0; m < 4; m++)
        #pragma unroll
        for(int n = 0; n < 4; n++) acc[m][n] = f4v{0.f, 0.f, 0.f, 0.f};
    #pragma unroll 1
    for(int t = -1; t < 32; t++){
        int nxt = t + 1;
        if(nxt < 32)
            stage2(A, B, 4096, 4096, nxt << 6, nxt << 6, la[nxt & 1], lb[nxt & 1], w, lane);
        if(t >= 0)
            mfma_block(la[t & 1], lb[t & 1], wm, wn, qr, grp, acc);
        __syncthreads();
    }
    po += (size_t)ksp * 4194304;
    #pragma unroll
    for(int m = 0; m < 4; m++){
        int rb = (mt << 7) + wm + m * 16 + (grp << 2);
        #pragma unroll
        for(int n = 0; n < 4; n++){
            int col = (nt << 7) + wn + n * 16 + qr;
            #pragma unroll
            for(int r = 0; r < 4; r++)
                po[(size_t)(rb + r) * 1024 + col] = acc[m][n][r];
        }
    }
}

// ---------------- partial reduce: out = p0 + p1 (fp32)
__global__ __launch_bounds__(256) void k_red(const float* p0, const float* p1, float* out){
    size_t idx = ((size_t)blockIdx.x * 256 + threadIdx.x) * 4;
    f4v a = *(const f4v*)&p0[idx];
    f4v b = *(const f4v*)&p1[idx];
    f4v s = a + b;
    *(f4v*)&out[idx] = s;
}

// ---------------- flash attention: 4 waves x 16 q-rows, q-tile 64, grid (16,32)=512
// K,V^T LDS dbuf via swizzled gload16; swapped QK^T; online softmax; natural q/k layout
__global__ __launch_bounds__(256) void k_attn(const short* qg, const short* kg,
                                              const short* vtg, short* res){
    __shared__ __align__(16) short lk[2][8192];   // [64 keys][128 d] swizzled
    __shared__ __align__(16) short lv[2][8192];   // [128 c][64 keys] swizzled
    __shared__ __align__(16) short pl[4][16 * 72];
    int bh = blockIdx.y, b = bh >> 3, h = bh & 7;
    int w = threadIdx.x >> 6, lane = threadIdx.x & 63;
    int qr = lane & 15, grp = lane >> 4;
    int q0 = blockIdx.x * 64 + w * 16;
    const short* vtb = vtg + ((size_t)bh << 17);
    short* pw = &pl[w][0];

    int tok = b * 1024 + q0 + qr;
    s8v qf[4];
    #pragma unroll
    for(int ks = 0; ks < 4; ks++)
        qf[ks] = *(const s8v*)&qg[(size_t)tok * 1024 + h * 128 + ks * 32 + grp * 8];
    f4v o[8];
    #pragma unroll
    for(int ct = 0; ct < 8; ct++) o[ct] = f4v{0.f, 0.f, 0.f, 0.f};
    float m_cur = -1e30f, l_cur = 0.f;

    int klr = lane >> 4, klc = lane & 15;
    int vlr = lane >> 3, vlc = lane & 7;

    #pragma unroll 1
    for(int t = -1; t < 16; t++){
        int nxt = t + 1;
        if(nxt < 16){
            int buf = nxt & 1, kv0 = nxt << 6;
            #pragma unroll
            for(int i = 0; i < 4; i++){
                int seg = (w << 2) + i;
                int kr = (seg << 2) + klr;
                int kc = klc ^ (kr & 7);
                gload16(&kg[(size_t)(b * 1024 + kv0 + kr) * 1024 + h * 128 + kc * 8], &lk[buf][seg << 9]);
                int vr = (seg << 3) + vlr;
                int vc = vlc ^ (vr & 7);
                gload16(&vtb[(size_t)vr * 1024 + kv0 + vc * 8], &lv[buf][seg << 9]);
            }
        }
        if(t >= 0){
            int cur = t & 1;
            f4v s[4];
            #pragma unroll
            for(int kt = 0; kt < 4; kt++) s[kt] = f4v{0.f, 0.f, 0.f, 0.f};
            __builtin_amdgcn_s_setprio(1);
            #pragma unroll
            for(int ks = 0; ks < 4; ks++){
                #pragma unroll
                for(int kt = 0; kt < 4; kt++){
                    int row = kt * 16 + qr;
                    s8v kf = *(const s8v*)&lk[cur][row * 128 + ((((ks << 2) + grp) ^ (row & 7)) << 3)];
                    s[kt] = __builtin_amdgcn_mfma_f32_16x16x32_bf16(kf, qf[ks], s[kt], 0, 0, 0);
                }
            }
            __builtin_amdgcn_s_setprio(0);
            float pm = s[0][0];
            #pragma unroll
            for(int kt = 0; kt < 4; kt++)
                #pragma unroll
                for(int r = 0; r < 4; r++) pm = fmaxf(pm, s[kt][r]);
            pm = fmaxf(pm, __shfl_xor(pm, 16));
            pm = fmaxf(pm, __shfl_xor(pm, 32));
            float mn = fmaxf(m_cur, pm);
            float fs = __expf(m_cur - mn);
            float ps = 0.f;
            #pragma unroll
            for(int kt = 0; kt < 4; kt++)
                #pragma unroll
                for(int r = 0; r < 4; r++){
                    s[kt][r] = __expf(s[kt][r] - mn);
                    ps += s[kt][r];
                }
            ps += __shfl_xor(ps, 16);
            ps += __shfl_xor(ps, 32);
            l_cur = l_cur * fs + ps;
            m_cur = mn;
            #pragma unroll
            for(int ct = 0; ct < 8; ct++){
                o[ct][0] *= fs; o[ct][1] *= fs; o[ct][2] *= fs; o[ct][3] *= fs;
            }
            #pragma unroll
            for(int kt = 0; kt < 4; kt++){
                s4v pvv;
                #pragma unroll
                for(int r = 0; r < 4; r++) pvv[r] = (short)f2b(s[kt][r]);
                *(s4v*)&pw[qr * 72 + kt * 16 + grp * 4] = pvv;
            }
            s8v pf0 = *(const s8v*)&pw[qr * 72 + grp * 8];
            s8v pf1 = *(const s8v*)&pw[qr * 72 + 32 + grp * 8];
            __builtin_amdgcn_s_setprio(1);
            #pragma unroll
            for(int ct = 0; ct < 8; ct++){
                int row = ct * 16 + qr;
                s8v vf0 = *(const s8v*)&lv[cur][row * 64 + ((grp ^ (row & 7)) << 3)];
                s8v vf1 = *(const s8v*)&lv[cur][row * 64 + (((4 + grp) ^ (row & 7)) << 3)];
                o[ct] = __builtin_amdgcn_mfma_f32_16x16x32_bf16(vf0, pf0, o[ct], 0, 0, 0);
                o[ct] = __builtin_amdgcn_mfma_f32_16x16x32_bf16(vf1, pf1, o[ct], 0, 0, 0);
            }
            __builtin_amdgcn_s_setprio(0);
        }
        __syncthreads();
    }
    float inv = 1.0f / l_cur;
    #pragma unroll
    for(int ct = 0; ct < 8; ct++){
        s4v sv;
        #pragma unroll
        for(int r = 0; r < 4; r++) sv[r] = (short)f2b(o[ct][r] * inv);
        *(s4v*)&res[(size_t)tok * 1024 + h * 128 + ct * 16 + grp * 4] = sv;
    }
}

// ---------------- expand res [t][h*128+c] -> resw [t][(h,e)*128+c] = res * wo[t][he]
__global__ __launch_bounds__(256) void k_expand(const short* res, const float* wo, short* resw){
    int idx = blockIdx.x * 256 + threadIdx.x;
    int t = idx >> 9;
    int u = idx & 511;
    int he = u >> 4, ci = u & 15;
    int h = he >> 2;
    float g = wo[(size_t)t * 32 + he];
    s8v r = *(const s8v*)&res[(size_t)t * 1024 + h * 128 + ci * 8];
    s8v v;
    #pragma unroll
    for(int j = 0; j < 8; j++) v[j] = (short)f2b(b2f(r[j]) * g);
    *(s8v*)&resw[(size_t)t * 4096 + u * 8] = v;
}

extern "C" void kernel_launch(void* const* d_in, const int* in_sizes, int n_in,
                              void* d_out, int out_size, void* d_ws, size_t ws_size,
                              hipStream_t stream){
    const float* q_src = (const float*)d_in[0];
    const float* k_src = (const float*)d_in[1];
    const float* v_src = (const float*)d_in[2];
    const float* Wq    = (const float*)d_in[3];
    const float* Wk    = (const float*)d_in[4];
    const float* Wv    = (const float*)d_in[5];
    const float* Wo    = (const float*)d_in[6];
    const float* selv  = (const float*)d_in[7];
    const float* selo  = (const float*)d_in[8];

    const size_t MB = 1ull << 20;
    char* ws = (char*)d_ws;
    short* qsb  = (short*)(ws + 0 * MB);    // [4096][1024] bf16  8MB
    short* ksb  = (short*)(ws + 8 * MB);    // 8MB
    short* vsb  = (short*)(ws + 16 * MB);   // 8MB
    short* wqb  = (short*)(ws + 24 * MB);   // 2MB
    short* wkb  = (short*)(ws + 26 * MB);   // 2MB
    short* wvt  = (short*)(ws + 28 * MB);   // [(he,c)=4096][1024] 8MB
    short* wot  = (short*)(ws + 36 * MB);   // [1024][4096] 8MB (live until o gemm)
    short* q    = (short*)(ws + 44 * MB);   // [4096 tok][1024] natural 8MB
    short* k    = (short*)(ws + 52 * MB);   // 8MB
    short* vt   = (short*)(ws + 60 * MB);   // [32bh][128][1024] 8MB
    short* res  = (short*)(ws + 68 * MB);   // [4096][1024] 8MB
    float* wv   = (float*)(ws + 76 * MB);   // [4096][32] 512KB
    float* wo   = (float*)(ws + 76 * MB + 524288);
    short* vall = (short*)(ws + 80 * MB);   // [4096][4096] bf16 32MB (dead after vredg)
    float* po   = (float*)(ws + 80 * MB);   // [2][4096][1024] fp32 32MB (reuses vall)
    short* resw = (short*)(ws + 0 * MB);    // [4096][4096] 32MB (reuses qsb..wvt region)

    const float qk_scale = 0.29730177875068026f; // 128^-0.25 applied to both q and k

    k_cvt<<<dim3(2048, 5), 256, 0, stream>>>(q_src, k_src, v_src, Wq, Wk, qsb, ksb, vsb, wqb, wkb);
    k_transpose<<<dim3(4, 32, 32), 256, 0, stream>>>(Wv, wvt, 1024, 128);
    k_transpose<<<dim3(32, 128, 1), 256, 0, stream>>>(Wo, wot, 4096, 1024);
    k_route<<<dim3(1024, 2), 256, 0, stream>>>(q_src, k_src, selv, selo, wv, wo);
    k_gemmqk<<<dim3(512), 256, 0, stream>>>(qsb, ksb, wqb, wkb, q, k, qk_scale);
    k_gemmva<<<dim3(1024), 256, 0, stream>>>(vsb, wvt, vall);
    k_vredg<<<dim3(32, 32), 256, 0, stream>>>(vall, wv, vt);
    k_attn<<<dim3(16, 32), 256, 0, stream>>>(q, k, vt, res);
    k_expand<<<dim3(8192), 256, 0, stream>>>(res, wo, resw);
    k_gemmo<<<dim3(512), 256, 0, stream>>>(resw, wot, po);
    k_red<<<dim3(4096), 256, 0, stream>>>(po, po + 4194304, (float*)d_out);
}

// Round 5
// 221.475 us; speedup vs baseline: 2.2725x; 1.1958x over previous
//
#include <hip/hip_runtime.h>

#define DEV __device__ __forceinline__

typedef __attribute__((ext_vector_type(8))) short s8v;
typedef __attribute__((ext_vector_type(4))) short s4v;
typedef __attribute__((ext_vector_type(4))) float f4v;

DEV unsigned short f2b(float f){
    unsigned u = __float_as_uint(f);
    u = (u + 0x7FFFu + ((u >> 16) & 1u)) >> 16;
    return (unsigned short)u;
}
DEV float b2f(short s){ return __uint_as_float(((unsigned)(unsigned short)s) << 16); }

DEV void gload16(const void* g, void* l){
    __builtin_amdgcn_global_load_lds(
        (const __attribute__((address_space(1))) unsigned*)g,
        (__attribute__((address_space(3))) unsigned*)l, 16, 0, 0);
}

// B=4, S=1024, D=1024, H=8, E=4, K=2, DH=128

// ---- shared GEMM pieces: 128x128 tile, BK=64, XOR-swizzled LDS ----
DEV void stage2(const short* A, const short* B, int sA, int sB, int kA, int kB,
                short* la, short* lb, int w, int lane){
    int srow = lane >> 3;
    int swcol = ((lane & 7) ^ srow) << 3;
    #pragma unroll
    for(int it = 0; it < 4; it++){
        int seg = (w << 2) + it;
        int row = (seg << 3) + srow;
        gload16(&A[(size_t)row * sA + kA + swcol], &la[seg << 9]);
        gload16(&B[(size_t)row * sB + kB + swcol], &lb[seg << 9]);
    }
}

DEV void mfma_block(const short* la, const short* lb, int wm, int wn, int qr, int grp, f4v acc[4][4]){
    #pragma unroll
    for(int ks = 0; ks < 2; ks++){
        s8v af[4], bf[4];
        #pragma unroll
        for(int m = 0; m < 4; m++)
            af[m] = *(const s8v*)&la[(wm + m * 16 + qr) * 64 + ((((ks << 2) + grp) ^ (qr & 7)) << 3)];
        #pragma unroll
        for(int n = 0; n < 4; n++)
            bf[n] = *(const s8v*)&lb[(wn + n * 16 + qr) * 64 + ((((ks << 2) + grp) ^ (qr & 7)) << 3)];
        #pragma unroll
        for(int m = 0; m < 4; m++)
            #pragma unroll
            for(int n = 0; n < 4; n++)
                acc[m][n] = __builtin_amdgcn_mfma_f32_16x16x32_bf16(af[m], bf[n], acc[m][n], 0, 0, 0);
    }
}

// ---------------- fp32 -> bf16 bulk convert
__global__ __launch_bounds__(256) void k_cvt(const float* s0, const float* s1, const float* s2,
                                             const float* s3, const float* s4,
                                             short* o0, short* o1, short* o2, short* o3, short* o4){
    int y = blockIdx.y;
    const float* s = (y == 0) ? s0 : (y == 1) ? s1 : (y == 2) ? s2 : (y == 3) ? s3 : s4;
    short* o = (y == 0) ? o0 : (y == 1) ? o1 : (y == 2) ? o2 : (y == 3) ? o3 : o4;
    int n8 = (y < 3) ? 524288 : 131072;
    int idx = blockIdx.x * 256 + threadIdx.x;
    if(idx < n8){
        const float4* f = (const float4*)(s + (size_t)idx * 8);
        float4 a = f[0], b = f[1];
        s8v v;
        v[0] = f2b(a.x); v[1] = f2b(a.y); v[2] = f2b(a.z); v[3] = f2b(a.w);
        v[4] = f2b(b.x); v[5] = f2b(b.y); v[6] = f2b(b.z); v[7] = f2b(b.w);
        *(s8v*)(o + (size_t)idx * 8) = v;
    }
}

// ---------------- transpose (fp32 in -> bf16 out), per-z slice [R][C] -> [C][R]
__global__ __launch_bounds__(256) void k_transpose(const float* in, short* out, int R, int C){
    in  += (size_t)blockIdx.z * R * C;
    out += (size_t)blockIdx.z * R * C;
    __shared__ float t[32][33];
    int c0 = blockIdx.x * 32, r0 = blockIdx.y * 32;
    int tx = threadIdx.x & 31, ty = threadIdx.x >> 5;
    #pragma unroll
    for(int p = 0; p < 4; p++){
        int r = p * 8 + ty;
        t[r][tx] = in[(size_t)(r0 + r) * C + c0 + tx];
    }
    __syncthreads();
    #pragma unroll
    for(int p = 0; p < 4; p++){
        int c = p * 8 + ty;
        out[(size_t)(c0 + c) * R + r0 + tx] = (short)f2b(t[tx][c]);
    }
}

// ---------------- routing logits: register-blocked fp32 GEMM, K-split x8
// grid (256, 2): blockIdx.x = tok-tile(32) x ksplit(8); y: 0=(k_src,selv) 1=(q_src,selo)
// thread owns 4 tokens x 4 experts; partials to part[ks][y][4096][32]
__global__ __launch_bounds__(256) void k_rlogits(const float* qsrc, const float* ksrc,
                                                 const float* selv, const float* selo,
                                                 float* part){
    int which = blockIdx.y;
    const float* src = which ? qsrc : ksrc;
    const float* sel = which ? selo : selv;
    int tt = blockIdx.x >> 3, ks = blockIdx.x & 7;
    int tok0 = tt << 7;
    __shared__ float lsrc[128][36];
    __shared__ float lsel[32][36];
    int tid = threadIdx.x;
    int ts = tid & 31, es = tid >> 5;
    float acc[4][4];
    #pragma unroll
    for(int j = 0; j < 4; j++)
        #pragma unroll
        for(int i = 0; i < 4; i++) acc[j][i] = 0.f;

    #pragma unroll 1
    for(int c = 0; c < 4; c++){
        int k0 = (ks << 7) + (c << 5);
        // stage src tile [128][32] (quad-rotated: quad slot = (q + row) & 7)
        {
            int row = tid >> 1, half = tid & 1;
            const float4* g = (const float4*)(src + (size_t)(tok0 + row) * 1024 + k0 + half * 16);
            #pragma unroll
            for(int qq = 0; qq < 4; qq++){
                int qw = half * 4 + qq;
                *(float4*)&lsrc[row][((qw + row) & 7) * 4] = g[qq];
            }
        }
        // stage sel tile [32][32]
        {
            int row = tid >> 3, qw = tid & 7;
            *(float4*)&lsel[row][((qw + row) & 7) * 4] =
                *(const float4*)(sel + (size_t)row * 1024 + k0 + qw * 4);
        }
        __syncthreads();
        #pragma unroll
        for(int q = 0; q < 8; q++){
            float4 sv[4];
            #pragma unroll
            for(int i = 0; i < 4; i++){
                int e = es * 4 + i;
                sv[i] = *(const float4*)&lsel[e][((q + e) & 7) * 4];
            }
            int slot = ((q + ts) & 7) * 4;
            #pragma unroll
            for(int j = 0; j < 4; j++){
                float4 xv = *(const float4*)&lsrc[ts + 32 * j][slot];
                #pragma unroll
                for(int i = 0; i < 4; i++){
                    acc[j][i] = fmaf(xv.x, sv[i].x, acc[j][i]);
                    acc[j][i] = fmaf(xv.y, sv[i].y, acc[j][i]);
                    acc[j][i] = fmaf(xv.z, sv[i].z, acc[j][i]);
                    acc[j][i] = fmaf(xv.w, sv[i].w, acc[j][i]);
                }
            }
        }
        __syncthreads();
    }
    #pragma unroll
    for(int j = 0; j < 4; j++){
        int token = tok0 + ts + 32 * j;
        f4v st;
        #pragma unroll
        for(int i = 0; i < 4; i++) st[i] = acc[j][i];
        *(f4v*)&part[(((size_t)(ks * 2 + which) * 4096) + token) * 32 + es * 4] = st;
    }
}

// ---------------- combine partials + sigmoid + top-2: grid (128, 2)
__global__ __launch_bounds__(256) void k_rfinal(const float* part, float* wvp, float* wop){
    int which = blockIdx.y;
    float* wout = which ? wop : wvp;
    int tid = threadIdx.x;
    int tok = blockIdx.x * 32 + (tid >> 3), h = tid & 7;
    f4v sum = {0.f, 0.f, 0.f, 0.f};
    #pragma unroll
    for(int s = 0; s < 8; s++)
        sum += *(const f4v*)&part[(((size_t)(s * 2 + which) * 4096) + tok) * 32 + h * 4];
    float g[4];
    #pragma unroll
    for(int e = 0; e < 4; e++) g[e] = 1.0f / (1.0f + expf(-sum[e]));
    f4v out;
    #pragma unroll
    for(int e = 0; e < 4; e++){
        int rank = 0;
        #pragma unroll
        for(int j = 0; j < 4; j++)
            rank += (g[j] > g[e]) || (g[j] == g[e] && j < e);
        out[e] = (rank < 2) ? g[e] : 0.0f;
    }
    *(f4v*)&wout[(size_t)tok * 32 + h * 4] = out;
}

// ---------------- fused Q+K projection GEMM: grid 512, natural-layout output [4096][1024]
__global__ __launch_bounds__(256) void k_gemmqk(const short* qsb, const short* ksb,
                                                const short* wqb, const short* wkb,
                                                short* qo, short* ko, float scale){
    __shared__ __align__(16) short la[2][8192];
    __shared__ __align__(16) short lb[2][8192];
    int wg = (blockIdx.x & 7) * 64 + (blockIdx.x >> 3);
    int which = wg >> 8, tl = wg & 255;
    int mt = tl >> 3, nt = tl & 7;
    const short* A = (which ? ksb : qsb) + ((size_t)(mt << 7)) * 1024;
    const short* B = (which ? wkb : wqb) + ((size_t)(nt << 7)) * 1024;
    short* out = which ? ko : qo;
    int tid = threadIdx.x, lane = tid & 63, w = tid >> 6;
    int wm = (w >> 1) << 6, wn = (w & 1) << 6;
    int qr = lane & 15, grp = lane >> 4;
    f4v acc[4][4];
    #pragma unroll
    for(int m = 0; m < 4; m++)
        #pragma unroll
        for(int n = 0; n < 4; n++) acc[m][n] = f4v{0.f, 0.f, 0.f, 0.f};
    #pragma unroll 1
    for(int t = -1; t < 16; t++){
        int nxt = t + 1;
        if(nxt < 16)
            stage2(A, B, 1024, 1024, nxt << 6, nxt << 6, la[nxt & 1], lb[nxt & 1], w, lane);
        if(t >= 0)
            mfma_block(la[t & 1], lb[t & 1], wm, wn, qr, grp, acc);
        __syncthreads();
    }
    #pragma unroll
    for(int m = 0; m < 4; m++){
        int rb = (mt << 7) + wm + m * 16 + (grp << 2);
        #pragma unroll
        for(int n = 0; n < 4; n++){
            int col = (nt << 7) + wn + n * 16 + qr;
            #pragma unroll
            for(int r = 0; r < 4; r++)
                out[(size_t)(rb + r) * 1024 + col] = (short)f2b(acc[m][n][r] * scale);
        }
    }
}

// ---------------- dense v_all GEMM: [4096 tok][1024] x [4096 (he,c)][1024]^T -> [4096][4096]
__global__ __launch_bounds__(256) void k_gemmva(const short* A, const short* B, short* C){
    __shared__ __align__(16) short la[8192];
    __shared__ __align__(16) short lb[8192];
    int wg = (blockIdx.x & 7) * 128 + (blockIdx.x >> 3);
    int mt = wg >> 5, nt = wg & 31;
    int i0 = mt << 7, j0 = nt << 7;
    const short* Ab = A + (size_t)i0 * 1024;
    const short* Bb = B + (size_t)j0 * 1024;
    int tid = threadIdx.x, lane = tid & 63, w = tid >> 6;
    int wm = (w >> 1) << 6, wn = (w & 1) << 6;
    int qr = lane & 15, grp = lane >> 4;
    f4v acc[4][4];
    #pragma unroll
    for(int m = 0; m < 4; m++)
        #pragma unroll
        for(int n = 0; n < 4; n++) acc[m][n] = f4v{0.f, 0.f, 0.f, 0.f};
    #pragma unroll 1
    for(int t = 0; t < 16; t++){
        stage2(Ab, Bb, 1024, 1024, t << 6, t << 6, la, lb, w, lane);
        __syncthreads();
        mfma_block(la, lb, wm, wn, qr, grp, acc);
        __syncthreads();
    }
    #pragma unroll
    for(int m = 0; m < 4; m++){
        int rb = i0 + wm + m * 16 + (grp << 2);
        #pragma unroll
        for(int n = 0; n < 4; n++){
            int col = j0 + wn + n * 16 + qr;
            #pragma unroll
            for(int r = 0; r < 4; r++)
                C[(size_t)(rb + r) * 4096 + col] = (short)f2b(acc[m][n][r]);
        }
    }
}

// ---------------- gated reduce over E=4 + transpose: vall -> vt [bh][c][s]
__global__ __launch_bounds__(256) void k_vredg(const short* vall, const float* wv, short* vtg){
    int bh = blockIdx.y, b = bh >> 3, h = bh & 7;
    int s0 = blockIdx.x * 32;
    constexpr int LDT = 520;
    __shared__ __align__(16) short tile[32 * LDT];
    __shared__ float gsm[32][4];
    int tid = threadIdx.x;
    #pragma unroll
    for(int p = 0; p < 8; p++){
        int chunk = tid + p * 256;
        int row = chunk >> 6, cc = (chunk & 63) << 3;
        int token = b * 1024 + s0 + row;
        *(s8v*)&tile[row * LDT + cc] = *(const s8v*)&vall[(size_t)token * 4096 + h * 512 + cc];
    }
    if(tid < 128){
        int row = tid >> 2, e = tid & 3;
        gsm[row][e] = wv[(size_t)(b * 1024 + s0 + row) * 32 + h * 4 + e];
    }
    __syncthreads();
    #pragma unroll
    for(int p = 0; p < 16; p++){
        int idx = tid + p * 256;
        int s = idx & 31, c = idx >> 5;
        float v = 0.f;
        #pragma unroll
        for(int e = 0; e < 4; e++) v += b2f(tile[s * LDT + e * 128 + c]) * gsm[s][e];
        vtg[((size_t)bh * 128 + c) * 1024 + s0 + s] = (short)f2b(v);
    }
}

// ---------------- O projection: grid 512 = (tile, K-half), fp32 partials
__global__ __launch_bounds__(256) void k_gemmo(const short* resw, const short* wot, float* po){
    __shared__ __align__(16) short la[2][8192];
    __shared__ __align__(16) short lb[2][8192];
    int wg = (blockIdx.x & 7) * 64 + (blockIdx.x >> 3);
    int ksp = wg & 1, tile = wg >> 1;
    int mt = tile >> 3, nt = tile & 7;
    const short* A = resw + (size_t)(mt << 7) * 4096 + ksp * 2048;
    const short* B = wot + (size_t)(nt << 7) * 4096 + ksp * 2048;
    int tid = threadIdx.x, lane = tid & 63, w = tid >> 6;
    int wm = (w >> 1) << 6, wn = (w & 1) << 6;
    int qr = lane & 15, grp = lane >> 4;
    f4v acc[4][4];
    #pragma unroll
    for(int m = 0; m < 4; m++)
        #pragma unroll
        for(int n = 0; n < 4; n++) acc[m][n] = f4v{0.f, 0.f, 0.f, 0.f};
    #pragma unroll 1
    for(int t = -1; t < 32; t++){
        int nxt = t + 1;
        if(nxt < 32)
            stage2(A, B, 4096, 4096, nxt << 6, nxt << 6, la[nxt & 1], lb[nxt & 1], w, lane);
        if(t >= 0)
            mfma_block(la[t & 1], lb[t & 1], wm, wn, qr, grp, acc);
        __syncthreads();
    }
    po += (size_t)ksp * 4194304;
    #pragma unroll
    for(int m = 0; m < 4; m++){
        int rb = (mt << 7) + wm + m * 16 + (grp << 2);
        #pragma unroll
        for(int n = 0; n < 4; n++){
            int col = (nt << 7) + wn + n * 16 + qr;
            #pragma unroll
            for(int r = 0; r < 4; r++)
                po[(size_t)(rb + r) * 1024 + col] = acc[m][n][r];
        }
    }
}

// ---------------- partial reduce: out = p0 + p1 (fp32)
__global__ __launch_bounds__(256) void k_red(const float* p0, const float* p1, float* out){
    size_t idx = ((size_t)blockIdx.x * 256 + threadIdx.x) * 4;
    f4v a = *(const f4v*)&p0[idx];
    f4v b = *(const f4v*)&p1[idx];
    f4v s = a + b;
    *(f4v*)&out[idx] = s;
}

// ---------------- flash attention: 4 waves x 16 q-rows, q-tile 64, grid (16,32)=512
__global__ __launch_bounds__(256) void k_attn(const short* qg, const short* kg,
                                              const short* vtg, short* res){
    __shared__ __align__(16) short lk[2][8192];
    __shared__ __align__(16) short lv[2][8192];
    __shared__ __align__(16) short pl[4][16 * 72];
    int bh = blockIdx.y, b = bh >> 3, h = bh & 7;
    int w = threadIdx.x >> 6, lane = threadIdx.x & 63;
    int qr = lane & 15, grp = lane >> 4;
    int q0 = blockIdx.x * 64 + w * 16;
    const short* vtb = vtg + ((size_t)bh << 17);
    short* pw = &pl[w][0];

    int tok = b * 1024 + q0 + qr;
    s8v qf[4];
    #pragma unroll
    for(int ks = 0; ks < 4; ks++)
        qf[ks] = *(const s8v*)&qg[(size_t)tok * 1024 + h * 128 + ks * 32 + grp * 8];
    f4v o[8];
    #pragma unroll
    for(int ct = 0; ct < 8; ct++) o[ct] = f4v{0.f, 0.f, 0.f, 0.f};
    float m_cur = -1e30f, l_cur = 0.f;

    int klr = lane >> 4, klc = lane & 15;
    int vlr = lane >> 3, vlc = lane & 7;

    #pragma unroll 1
    for(int t = -1; t < 16; t++){
        int nxt = t + 1;
        if(nxt < 16){
            int buf = nxt & 1, kv0 = nxt << 6;
            #pragma unroll
            for(int i = 0; i < 4; i++){
                int seg = (w << 2) + i;
                int kr = (seg << 2) + klr;
                int kc = klc ^ (kr & 7);
                gload16(&kg[(size_t)(b * 1024 + kv0 + kr) * 1024 + h * 128 + kc * 8], &lk[buf][seg << 9]);
                int vr = (seg << 3) + vlr;
                int vc = vlc ^ (vr & 7);
                gload16(&vtb[(size_t)vr * 1024 + kv0 + vc * 8], &lv[buf][seg << 9]);
            }
        }
        if(t >= 0){
            int cur = t & 1;
            f4v s[4];
            #pragma unroll
            for(int kt = 0; kt < 4; kt++) s[kt] = f4v{0.f, 0.f, 0.f, 0.f};
            __builtin_amdgcn_s_setprio(1);
            #pragma unroll
            for(int ks = 0; ks < 4; ks++){
                #pragma unroll
                for(int kt = 0; kt < 4; kt++){
                    int row = kt * 16 + qr;
                    s8v kf = *(const s8v*)&lk[cur][row * 128 + ((((ks << 2) + grp) ^ (row & 7)) << 3)];
                    s[kt] = __builtin_amdgcn_mfma_f32_16x16x32_bf16(kf, qf[ks], s[kt], 0, 0, 0);
                }
            }
            __builtin_amdgcn_s_setprio(0);
            float pm = s[0][0];
            #pragma unroll
            for(int kt = 0; kt < 4; kt++)
                #pragma unroll
                for(int r = 0; r < 4; r++) pm = fmaxf(pm, s[kt][r]);
            pm = fmaxf(pm, __shfl_xor(pm, 16));
            pm = fmaxf(pm, __shfl_xor(pm, 32));
            float mn = fmaxf(m_cur, pm);
            float fs = __expf(m_cur - mn);
            float ps = 0.f;
            #pragma unroll
            for(int kt = 0; kt < 4; kt++)
                #pragma unroll
                for(int r = 0; r < 4; r++){
                    s[kt][r] = __expf(s[kt][r] - mn);
                    ps += s[kt][r];
                }
            ps += __shfl_xor(ps, 16);
            ps += __shfl_xor(ps, 32);
            l_cur = l_cur * fs + ps;
            m_cur = mn;
            #pragma unroll
            for(int ct = 0; ct < 8; ct++){
                o[ct][0] *= fs; o[ct][1] *= fs; o[ct][2] *= fs; o[ct][3] *= fs;
            }
            #pragma unroll
            for(int kt = 0; kt < 4; kt++){
                s4v pvv;
                #pragma unroll
                for(int r = 0; r < 4; r++) pvv[r] = (short)f2b(s[kt][r]);
                *(s4v*)&pw[qr * 72 + kt * 16 + grp * 4] = pvv;
            }
            s8v pf0 = *(const s8v*)&pw[qr * 72 + grp * 8];
            s8v pf1 = *(const s8v*)&pw[qr * 72 + 32 + grp * 8];
            __builtin_amdgcn_s_setprio(1);
            #pragma unroll
            for(int ct = 0; ct < 8; ct++){
                int row = ct * 16 + qr;
                s8v vf0 = *(const s8v*)&lv[cur][row * 64 + ((grp ^ (row & 7)) << 3)];
                s8v vf1 = *(const s8v*)&lv[cur][row * 64 + (((4 + grp) ^ (row & 7)) << 3)];
                o[ct] = __builtin_amdgcn_mfma_f32_16x16x32_bf16(vf0, pf0, o[ct], 0, 0, 0);
                o[ct] = __builtin_amdgcn_mfma_f32_16x16x32_bf16(vf1, pf1, o[ct], 0, 0, 0);
            }
            __builtin_amdgcn_s_setprio(0);
        }
        __syncthreads();
    }
    float inv = 1.0f / l_cur;
    #pragma unroll
    for(int ct = 0; ct < 8; ct++){
        s4v sv;
        #pragma unroll
        for(int r = 0; r < 4; r++) sv[r] = (short)f2b(o[ct][r] * inv);
        *(s4v*)&res[(size_t)tok * 1024 + h * 128 + ct * 16 + grp * 4] = sv;
    }
}

// ---------------- expand res [t][h*128+c] -> resw [t][(h,e)*128+c] = res * wo[t][he]
__global__ __launch_bounds__(256) void k_expand(const short* res, const float* wo, short* resw){
    int idx = blockIdx.x * 256 + threadIdx.x;
    int t = idx >> 9;
    int u = idx & 511;
    int he = u >> 4, ci = u & 15;
    int h = he >> 2;
    float g = wo[(size_t)t * 32 + he];
    s8v r = *(const s8v*)&res[(size_t)t * 1024 + h * 128 + ci * 8];
    s8v v;
    #pragma unroll
    for(int j = 0; j < 8; j++) v[j] = (short)f2b(b2f(r[j]) * g);
    *(s8v*)&resw[(size_t)t * 4096 + u * 8] = v;
}

extern "C" void kernel_launch(void* const* d_in, const int* in_sizes, int n_in,
                              void* d_out, int out_size, void* d_ws, size_t ws_size,
                              hipStream_t stream){
    const float* q_src = (const float*)d_in[0];
    const float* k_src = (const float*)d_in[1];
    const float* v_src = (const float*)d_in[2];
    const float* Wq    = (const float*)d_in[3];
    const float* Wk    = (const float*)d_in[4];
    const float* Wv    = (const float*)d_in[5];
    const float* Wo    = (const float*)d_in[6];
    const float* selv  = (const float*)d_in[7];
    const float* selo  = (const float*)d_in[8];

    const size_t MB = 1ull << 20;
    char* ws = (char*)d_ws;
    short* qsb  = (short*)(ws + 0 * MB);    // [4096][1024] bf16  8MB
    short* ksb  = (short*)(ws + 8 * MB);    // 8MB
    short* vsb  = (short*)(ws + 16 * MB);   // 8MB
    short* wqb  = (short*)(ws + 24 * MB);   // 2MB
    short* wkb  = (short*)(ws + 26 * MB);   // 2MB
    short* wvt  = (short*)(ws + 28 * MB);   // [(he,c)=4096][1024] 8MB
    short* wot  = (short*)(ws + 36 * MB);   // [1024][4096] 8MB (live until o gemm)
    short* q    = (short*)(ws + 44 * MB);   // [4096 tok][1024] natural 8MB
    short* k    = (short*)(ws + 52 * MB);   // 8MB
    short* vt   = (short*)(ws + 60 * MB);   // [32bh][128][1024] 8MB
    short* res  = (short*)(ws + 68 * MB);   // [4096][1024] 8MB
    float* wv   = (float*)(ws + 76 * MB);   // [4096][32] 512KB
    float* wo   = (float*)(ws + 76 * MB + 524288);
    float* part = (float*)(ws + 80 * MB);   // [8][2][4096][32] fp32 8.4MB (dead after rfinal)
    short* vall = (short*)(ws + 80 * MB);   // [4096][4096] bf16 32MB (after part dead)
    float* po   = (float*)(ws + 80 * MB);   // [2][4096][1024] fp32 32MB (reuses vall)
    short* resw = (short*)(ws + 0 * MB);    // [4096][4096] 32MB (reuses qsb..wvt region)

    const float qk_scale = 0.29730177875068026f; // 128^-0.25 applied to both q and k

    k_cvt<<<dim3(2048, 5), 256, 0, stream>>>(q_src, k_src, v_src, Wq, Wk, qsb, ksb, vsb, wqb, wkb);
    k_transpose<<<dim3(4, 32, 32), 256, 0, stream>>>(Wv, wvt, 1024, 128);
    k_transpose<<<dim3(32, 128, 1), 256, 0, stream>>>(Wo, wot, 4096, 1024);
    k_rlogits<<<dim3(256, 2), 256, 0, stream>>>(q_src, k_src, selv, selo, part);
    k_rfinal<<<dim3(128, 2), 256, 0, stream>>>(part, wv, wo);
    k_gemmqk<<<dim3(512), 256, 0, stream>>>(qsb, ksb, wqb, wkb, q, k, qk_scale);
    k_gemmva<<<dim3(1024), 256, 0, stream>>>(vsb, wvt, vall);
    k_vredg<<<dim3(32, 32), 256, 0, stream>>>(vall, wv, vt);
    k_attn<<<dim3(16, 32), 256, 0, stream>>>(q, k, vt, res);
    k_expand<<<dim3(8192), 256, 0, stream>>>(res, wo, resw);
    k_gemmo<<<dim3(512), 256, 0, stream>>>(resw, wot, po);
    k_red<<<dim3(4096), 256, 0, stream>>>(po, po + 4194304, (float*)d_out);
}